// Round 12
// baseline (1139.249 us; speedup 1.0000x reference)
//
#include <hip/hip_runtime.h>
#include <hip/hip_bf16.h>

#define NREL 3
#define EMB 32
#define HID 64

typedef __attribute__((ext_vector_type(8))) short short8_t;
typedef __attribute__((ext_vector_type(4))) short short4_t;
typedef __attribute__((ext_vector_type(4))) float f32x4;

__device__ inline short f2bf(float v) {
  __hip_bfloat16 b = __float2bfloat16(v);
  short s;
  __builtin_memcpy(&s, &b, 2);
  return s;
}
__device__ inline float bf2f(short s) {
  __hip_bfloat16 b;
  __builtin_memcpy(&b, &s, 2);
  return __bfloat162float(b);
}
__device__ inline void split8(const float* v, short8_t* h, short8_t* l) {
#pragma unroll
  for (int i = 0; i < 8; i++) {
    short hh = f2bf(v[i]);
    (*h)[i] = hh;
    (*l)[i] = f2bf(v[i] - bf2f(hh));
  }
}

// ---- fused prep: embedding (hi/lo) + BUCKET histogram (dst>>6) + weight prep ----
__global__ __launch_bounds__(256) void prep_k(
    const int* __restrict__ sid, const int* __restrict__ cid, const int* __restrict__ pid,
    const float* __restrict__ se, const float* __restrict__ ce, const float* __restrict__ pe,
    short* __restrict__ xh, short* __restrict__ xl,
    const int* __restrict__ dst, int* __restrict__ bcnt,
    const float* __restrict__ root1, const float* __restrict__ W1,
    const float* __restrict__ root2, const float* __restrict__ W2,
    short* __restrict__ w1h, short* __restrict__ w1l,
    short* __restrict__ w2h, short* __restrict__ w2l, int N, int E) {
  int i = blockIdx.x * 256 + threadIdx.x;
  if (i < N * 8) {  // embedding: one float4 slice per thread
    int n = i >> 3, cg = i & 7;
    const float4 a = *(const float4*)&se[sid[n] * EMB + cg * 4];
    const float4 b = *(const float4*)&ce[cid[n] * EMB + cg * 4];
    const float4 c = *(const float4*)&pe[pid[n] * EMB + cg * 4];
    float v[4];
    v[0] = a.x + b.x + c.x; v[1] = a.y + b.y + c.y;
    v[2] = a.z + b.z + c.z; v[3] = a.w + b.w + c.w;
    short4_t h, l;
#pragma unroll
    for (int j = 0; j < 4; j++) {
      short hh = f2bf(v[j]);
      h[j] = hh;
      l[j] = f2bf(v[j] - bf2f(hh));
    }
    *(short4_t*)&xh[(size_t)n * EMB + cg * 4] = h;
    *(short4_t*)&xl[(size_t)n * EMB + cg * 4] = l;
  }
  if (i < E) atomicAdd(&bcnt[dst[i] >> 6], 1);
  if (i < 64 * 128) {  // layer-1 weights
    int k = i >> 6, n = i & 63;
    float v = (k < EMB) ? root1[k * 64 + n] : W1[(k - EMB) * 64 + n];
    short h = f2bf(v);
    w1h[n * 128 + k] = h;
    w1l[n * 128 + k] = f2bf(v - bf2f(h));
  }
  if (i < 64 * 256) {  // layer-2 weights
    int k = i >> 6, n = i & 63;
    float v = (k < HID) ? root2[k * 64 + n] : W2[(k - HID) * 64 + n];
    short h = f2bf(v);
    w2h[n * 256 + k] = h;
    w2l[n * 256 + k] = f2bf(v - bf2f(h));
  }
}

// single-block exclusive scan over NBk buckets -> boffs (+sentinel) and bcur copy
__global__ __launch_bounds__(256) void bscan_k(const int* __restrict__ bcnt,
                                               int* __restrict__ boffs,
                                               int* __restrict__ bcur, int NBk) {
  __shared__ int tmp[256];
  __shared__ int carry_s;
  if (threadIdx.x == 0) carry_s = 0;
  __syncthreads();
  for (int base = 0; base < NBk; base += 256) {
    int i = base + threadIdx.x;
    int v = (i < NBk) ? bcnt[i] : 0;
    tmp[threadIdx.x] = v;
    __syncthreads();
    for (int off = 1; off < 256; off <<= 1) {
      int u = (threadIdx.x >= off) ? tmp[threadIdx.x - off] : 0;
      __syncthreads();
      tmp[threadIdx.x] += u;
      __syncthreads();
    }
    int carry = carry_s;
    if (i < NBk) {
      int ex = carry + tmp[threadIdx.x] - v;
      boffs[i] = ex;
      bcur[i] = ex;
    }
    __syncthreads();
    if (threadIdx.x == 0) carry_s = carry + tmp[255];
    __syncthreads();
  }
  if (threadIdx.x == 0) boffs[NBk] = carry_s;  // = E
}

// bucketize: append packed edge (dloc<<21 | et<<19 | src) at bucket cursor.
// Writes are sequential-within-bucket -> L2 lines fill completely (no 64B amplification).
__global__ __launch_bounds__(256) void bscatter_k(const int* __restrict__ src,
                                                  const int* __restrict__ dst,
                                                  const int* __restrict__ et,
                                                  int* __restrict__ bcur,
                                                  unsigned* __restrict__ pk, int E) {
  int e = blockIdx.x * 256 + threadIdx.x;
  if (e >= E) return;
  int d = dst[e];
  int pos = atomicAdd(&bcur[d >> 6], 1);
  pk[pos] = ((unsigned)(d & 63) << 21) | ((unsigned)et[e] << 19) | (unsigned)src[e];
}

// ====== layer-1 fused: edge-driven LDS accumulation + phased MFMA ======
// A: w1h+zero -> LDS, self -> regs; E: per-edge ds_add_f32 into 33-padded table;
// Ca: mean/split per-lane from acc_s, hi MFMAs; St: w1l; Cb: lo MFMAs.
__global__ __launch_bounds__(256) void l1fused_k(
    const short* __restrict__ xh, const short* __restrict__ xl,
    const int* __restrict__ boffs, const unsigned* __restrict__ pk,
    const short* __restrict__ wth, const short* __restrict__ wtl,
    const float* __restrict__ bias, short* __restrict__ h1h, short* __restrict__ h1l, int N) {
  __shared__ __align__(16) short lws[64][16][8];  // 16 KB (one plane)
  __shared__ float acc_s[192][33];                // 25.3 KB, +1 pad => conflict-free
  __shared__ int cnt_s[192];

  const int t = threadIdx.x;
  const int lane = t & 63, w = t >> 6;
  const int m_ = lane & 15, q = lane >> 4;
  const int n0b = blockIdx.x * 64;

  // ---- phase A ----
  int node_c = n0b + w * 16 + m_;
  if (node_c >= N) node_c = N - 1;
  short8_t ah0 = *(const short8_t*)&xh[(size_t)node_c * EMB + q * 8];
  short8_t al0 = *(const short8_t*)&xl[(size_t)node_c * EMB + q * 8];
#pragma unroll
  for (int i = 0; i < 4; i++) {
    int chi = t + 256 * i;
    int row = chi >> 4, c = chi & 15;
    short8_t wv = *(const short8_t*)&wth[(size_t)row * 128 + c * 8];
    *(short8_t*)&lws[row][c ^ (row & 7)][0] = wv;
  }
  for (int i = t; i < 192 * 33; i += 256) ((float*)acc_s)[i] = 0.f;
  if (t < 192) cnt_s[t] = 0;
  __syncthreads();

  // ---- phase E: edge-driven accumulation (4 threads per edge) ----
  {
    int beg = boffs[blockIdx.x], end = boffs[blockIdx.x + 1];
    const int qq = t & 3;
    for (int e = beg + (t >> 2); e < end; e += 64) {
      unsigned p = pk[e];
      int srcn = p & 0x7FFFF;
      int slot = ((p >> 19) & 3) * 64 + (int)(p >> 21);
      short8_t v = *(const short8_t*)&xh[(size_t)srcn * EMB + qq * 8];
#pragma unroll
      for (int i = 0; i < 8; i++) atomicAdd(&acc_s[slot][qq * 8 + i], bf2f(v[i]));
      if (qq == 0) atomicAdd(&cnt_s[slot], 1);
    }
  }
  __syncthreads();

  // ---- phase Ca: mean/split per lane, hi-plane MFMAs; latch a-fragments ----
  f32x4 acc[4];
#pragma unroll
  for (int i = 0; i < 4; i++) acc[i] = (f32x4){0.f, 0.f, 0.f, 0.f};
  short8_t ahv[4], alv[4];
#pragma unroll
  for (int g = 0; g < 4; g++) {
    if (g == 0) {
      ahv[0] = ah0;
      alv[0] = al0;
    } else {
      int slot = (g - 1) * 64 + w * 16 + m_;
      float inv = 1.f / fmaxf((float)cnt_s[slot], 1.f);
      float a[8];
#pragma unroll
      for (int i = 0; i < 8; i++) a[i] = acc_s[slot][q * 8 + i] * inv;
      split8(a, &ahv[g], &alv[g]);
    }
#pragma unroll
    for (int tt = 0; tt < 4; tt++) {
      int row = 16 * tt + m_;
      int cs = (g * 4 + q) ^ (row & 7);
      short8_t bh = *(const short8_t*)&lws[row][cs][0];
      acc[tt] = __builtin_amdgcn_mfma_f32_16x16x32_bf16(ahv[g], bh, acc[tt], 0, 0, 0);
      acc[tt] = __builtin_amdgcn_mfma_f32_16x16x32_bf16(alv[g], bh, acc[tt], 0, 0, 0);
    }
  }
  __syncthreads();

  // ---- phase St: stage lo-plane weights ----
#pragma unroll
  for (int i = 0; i < 4; i++) {
    int chi = t + 256 * i;
    int row = chi >> 4, c = chi & 15;
    short8_t wv = *(const short8_t*)&wtl[(size_t)row * 128 + c * 8];
    *(short8_t*)&lws[row][c ^ (row & 7)][0] = wv;
  }
  __syncthreads();

  // ---- phase Cb: lo-plane MFMAs ----
#pragma unroll
  for (int g = 0; g < 4; g++) {
#pragma unroll
    for (int tt = 0; tt < 4; tt++) {
      int row = 16 * tt + m_;
      int cs = (g * 4 + q) ^ (row & 7);
      short8_t bl = *(const short8_t*)&lws[row][cs][0];
      acc[tt] = __builtin_amdgcn_mfma_f32_16x16x32_bf16(ahv[g], bl, acc[tt], 0, 0, 0);
    }
  }
  // epilogue: bias + relu + hi/lo split store
#pragma unroll
  for (int tt = 0; tt < 4; tt++) {
    float bia = bias[16 * tt + m_];
#pragma unroll
    for (int reg = 0; reg < 4; reg++) {
      int node = n0b + w * 16 + q * 4 + reg;
      if (node < N) {
        float val = fmaxf(acc[tt][reg] + bia, 0.f);
        short hh = f2bf(val);
        h1h[(size_t)node * HID + 16 * tt + m_] = hh;
        h1l[(size_t)node * HID + 16 * tt + m_] = f2bf(val - bf2f(hh));
      }
    }
  }
}

// ====== layer-2 fused: edge-driven accumulation per K-half + phased MFMA ======
__global__ __launch_bounds__(256) void l2fused_k(
    const short* __restrict__ h1h, const short* __restrict__ h1l,
    const int* __restrict__ boffs, const unsigned* __restrict__ pk,
    const short* __restrict__ wth, const short* __restrict__ wtl,
    const float* __restrict__ bias, const float* __restrict__ linW,
    const int* __restrict__ batch, float* __restrict__ gs, float* __restrict__ gc, int N) {
  __shared__ __align__(16) short lws[64][16][8];  // 16 KB (one plane, one K-half)
  __shared__ float acc_s[192][33];                // 25.3 KB
  __shared__ int cnt_s[192];

  const int t = threadIdx.x;
  const int lane = t & 63, w = t >> 6;
  const int m_ = lane & 15, q = lane >> 4;
  const int n0b = blockIdx.x * 64;

  // ---- phase A: self -> regs; hi-weights(s0) -> LDS; zero acc ----
  int node_c = n0b + w * 16 + m_;
  if (node_c >= N) node_c = N - 1;
  short8_t ash[2], asl[2];
#pragma unroll
  for (int s_ = 0; s_ < 2; s_++) {
    ash[s_] = *(const short8_t*)&h1h[(size_t)node_c * HID + s_ * 32 + q * 8];
    asl[s_] = *(const short8_t*)&h1l[(size_t)node_c * HID + s_ * 32 + q * 8];
  }
#pragma unroll
  for (int i = 0; i < 4; i++) {
    int chi = t + 256 * i;
    int row = chi >> 4, c = chi & 15;
    int g = c >> 2, qq = c & 3;
    short8_t wv = *(const short8_t*)&wth[(size_t)row * 256 + g * 64 + 0 * 32 + qq * 8];
    *(short8_t*)&lws[row][c ^ (row & 7)][0] = wv;
  }
  for (int i = t; i < 192 * 33; i += 256) ((float*)acc_s)[i] = 0.f;
  if (t < 192) cnt_s[t] = 0;
  __syncthreads();

  f32x4 acc[4];
#pragma unroll
  for (int i = 0; i < 4; i++) acc[i] = (f32x4){0.f, 0.f, 0.f, 0.f};

  const int beg = boffs[blockIdx.x], end = boffs[blockIdx.x + 1];
  const int qq = t & 3;

#pragma unroll
  for (int s_ = 0; s_ < 2; s_++) {
    if (s_ == 1) {  // re-zero acc/cnt and stage hi-weights(s1)
      for (int i = t; i < 192 * 33; i += 256) ((float*)acc_s)[i] = 0.f;
      if (t < 192) cnt_s[t] = 0;
#pragma unroll
      for (int i = 0; i < 4; i++) {
        int chi = t + 256 * i;
        int row = chi >> 4, c = chi & 15;
        int g = c >> 2, q2 = c & 3;
        short8_t wv = *(const short8_t*)&wth[(size_t)row * 256 + g * 64 + 32 + q2 * 8];
        *(short8_t*)&lws[row][c ^ (row & 7)][0] = wv;
      }
      __syncthreads();
    }
    // ---- phase E(s_): edge-driven accumulation of neighbor hi-plane half-rows ----
    for (int e = beg + (t >> 2); e < end; e += 64) {
      unsigned p = pk[e];
      int srcn = p & 0x7FFFF;
      int slot = ((p >> 19) & 3) * 64 + (int)(p >> 21);
      short8_t v = *(const short8_t*)&h1h[(size_t)srcn * HID + s_ * 32 + qq * 8];
#pragma unroll
      for (int i = 0; i < 8; i++) atomicAdd(&acc_s[slot][qq * 8 + i], bf2f(v[i]));
      if (qq == 0) atomicAdd(&cnt_s[slot], 1);
    }
    __syncthreads();

    // ---- phase Ca(s_): mean/split per lane, hi-plane MFMAs; latch a-fragments ----
    short8_t ahv[4], alv[4];
#pragma unroll
    for (int g = 0; g < 4; g++) {
      if (g == 0) {
        ahv[0] = ash[s_];
        alv[0] = asl[s_];
      } else {
        int slot = (g - 1) * 64 + w * 16 + m_;
        float inv = 1.f / fmaxf((float)cnt_s[slot], 1.f);
        float a[8];
#pragma unroll
        for (int i = 0; i < 8; i++) a[i] = acc_s[slot][q * 8 + i] * inv;
        split8(a, &ahv[g], &alv[g]);
      }
#pragma unroll
      for (int tt = 0; tt < 4; tt++) {
        int row = 16 * tt + m_;
        int cs = (g * 4 + q) ^ (row & 7);
        short8_t bh = *(const short8_t*)&lws[row][cs][0];
        acc[tt] = __builtin_amdgcn_mfma_f32_16x16x32_bf16(ahv[g], bh, acc[tt], 0, 0, 0);
        acc[tt] = __builtin_amdgcn_mfma_f32_16x16x32_bf16(alv[g], bh, acc[tt], 0, 0, 0);
      }
    }
    __syncthreads();

    // ---- phase St(s_): stage lo-plane weights for this K-half ----
#pragma unroll
    for (int i = 0; i < 4; i++) {
      int chi = t + 256 * i;
      int row = chi >> 4, c = chi & 15;
      int g = c >> 2, q2 = c & 3;
      short8_t wv = *(const short8_t*)&wtl[(size_t)row * 256 + g * 64 + s_ * 32 + q2 * 8];
      *(short8_t*)&lws[row][c ^ (row & 7)][0] = wv;
    }
    __syncthreads();

    // ---- phase Cb(s_): lo-plane MFMAs (a-fragments from regs) ----
#pragma unroll
    for (int g = 0; g < 4; g++) {
#pragma unroll
      for (int tt = 0; tt < 4; tt++) {
        int row = 16 * tt + m_;
        int cs = (g * 4 + q) ^ (row & 7);
        short8_t bl = *(const short8_t*)&lws[row][cs][0];
        acc[tt] = __builtin_amdgcn_mfma_f32_16x16x32_bf16(ahv[g], bl, acc[tt], 0, 0, 0);
      }
    }
    if (s_ == 0) __syncthreads();  // protect lws/acc before s1 overwrites
  }

  // ---- pooled epilogue ----
  float bia[4], lw0[4], lw1[4];
#pragma unroll
  for (int tt = 0; tt < 4; tt++) {
    int col = 16 * tt + m_;
    bia[tt] = bias[col];
    lw0[tt] = linW[col * 2 + 0];
    lw1[tt] = linW[col * 2 + 1];
  }
#pragma unroll
  for (int reg = 0; reg < 4; reg++) {
    int node = n0b + w * 16 + q * 4 + reg;
    float p0 = 0.f, p1 = 0.f;
#pragma unroll
    for (int tt = 0; tt < 4; tt++) {
      float v = fmaxf(acc[tt][reg] + bia[tt], 0.f);
      p0 += v * lw0[tt];
      p1 += v * lw1[tt];
    }
#pragma unroll
    for (int o = 1; o < 16; o <<= 1) {
      p0 += __shfl_xor(p0, o, 64);
      p1 += __shfl_xor(p1, o, 64);
    }
    if (m_ == 0 && node < N) {
      int g = batch[node];
      atomicAdd(&gs[g * 2 + 0], p0);
      atomicAdd(&gs[g * 2 + 1], p1);
      atomicAdd(&gc[g], 1.0f);
    }
  }
}

__global__ __launch_bounds__(256) void final_k(const float* __restrict__ gs,
                                               const float* __restrict__ gc,
                                               const float* __restrict__ linb,
                                               float* __restrict__ out, int G) {
  int i = blockIdx.x * 256 + threadIdx.x;
  if (i >= G * 2) return;
  int g = i >> 1, o = i & 1;
  out[i] = gs[i] / fmaxf(gc[g], 1.0f) + linb[o];
}

extern "C" void kernel_launch(void* const* d_in, const int* in_sizes, int n_in,
                              void* d_out, int out_size, void* d_ws, size_t ws_size,
                              hipStream_t stream) {
  const int* sid = (const int*)d_in[0];
  const int* cid = (const int*)d_in[1];
  const int* pid = (const int*)d_in[2];
  const int* ei = (const int*)d_in[3];
  const int* et = (const int*)d_in[4];
  const int* batch = (const int*)d_in[5];
  const float* se = (const float*)d_in[7];
  const float* ce = (const float*)d_in[8];
  const float* pe = (const float*)d_in[9];
  const float* W1 = (const float*)d_in[10];
  const float* root1 = (const float*)d_in[11];
  const float* b1 = (const float*)d_in[12];
  const float* W2 = (const float*)d_in[13];
  const float* root2 = (const float*)d_in[14];
  const float* b2 = (const float*)d_in[15];
  const float* linW = (const float*)d_in[16];
  const float* linb = (const float*)d_in[17];
  float* out = (float*)d_out;

  const int N = in_sizes[0];
  const int E = in_sizes[4];
  const int G = out_size / 2;
  const int* src = ei;
  const int* dst = ei + E;
  const int NBk = (N + 63) / 64;       // buckets == l1/l2 blocks
  const int NBa = (NBk + 15) & ~15;    // aligned allocation

  // ---- workspace layout (16B-aligned blocks) ----
  char* w = (char*)d_ws;
  short* h1h = (short*)w;  w += (size_t)N * HID * sizeof(short);
  short* h1l = (short*)w;  w += (size_t)N * HID * sizeof(short);
  short* xh = (short*)w;   w += (size_t)N * EMB * sizeof(short);
  short* xl = (short*)w;   w += (size_t)N * EMB * sizeof(short);
  float* gs = (float*)w;   w += (size_t)G * 2 * sizeof(float);
  float* gc = (float*)w;   w += (size_t)G * sizeof(float);
  int* bcnt = (int*)w;     w += (size_t)NBa * sizeof(int);
  int* bcur = (int*)w;     w += (size_t)NBa * sizeof(int);
  int* boffs = (int*)w;    w += (size_t)(NBa + 16) * sizeof(int);
  unsigned* pk = (unsigned*)w; w += (size_t)E * sizeof(unsigned);
  short* w1h = (short*)w;  w += (size_t)64 * 128 * sizeof(short);
  short* w1l = (short*)w;  w += (size_t)64 * 128 * sizeof(short);
  short* w2h = (short*)w;  w += (size_t)64 * 256 * sizeof(short);
  short* w2l = (short*)w;  w += (size_t)64 * 256 * sizeof(short);
  if ((size_t)(w - (char*)d_ws) > ws_size) return;  // fail loudly, no OOB

  hipMemsetAsync(bcnt, 0, (size_t)NBa * sizeof(int), stream);
  hipMemsetAsync(gs, 0, (size_t)G * 3 * sizeof(float), stream);

  int prep_n = N * 8;  // covers E (1.5M) and weight ranges too for this problem size
  if (prep_n < E) prep_n = E;
  if (prep_n < 64 * 256) prep_n = 64 * 256;
  prep_k<<<(prep_n + 255) / 256, 256, 0, stream>>>(sid, cid, pid, se, ce, pe, xh, xl, dst,
                                                   bcnt, root1, W1, root2, W2, w1h, w1l, w2h,
                                                   w2l, N, E);
  bscan_k<<<1, 256, 0, stream>>>(bcnt, boffs, bcur, NBk);
  bscatter_k<<<(E + 255) / 256, 256, 0, stream>>>(src, dst, et, bcur, pk, E);

  l1fused_k<<<NBk, 256, 0, stream>>>(xh, xl, boffs, pk, w1h, w1l, b1, h1h, h1l, N);
  l2fused_k<<<NBk, 256, 0, stream>>>(h1h, h1l, boffs, pk, w2h, w2l, b2, linW, batch, gs, gc,
                                     N);
  final_k<<<(G * 2 + 255) / 256, 256, 0, stream>>>(gs, gc, linb, out, G);
}

// Round 13
// 468.740 us; speedup vs baseline: 2.4304x; 2.4304x over previous
//
#include <hip/hip_runtime.h>
#include <hip/hip_bf16.h>

#define NREL 3
#define EMB 32
#define HID 64
#define OVCAP 1024

typedef __attribute__((ext_vector_type(8))) short short8_t;
typedef __attribute__((ext_vector_type(4))) short short4_t;
typedef __attribute__((ext_vector_type(4))) float f32x4;

__device__ inline short f2bf(float v) {
  __hip_bfloat16 b = __float2bfloat16(v);
  short s;
  __builtin_memcpy(&s, &b, 2);
  return s;
}
__device__ inline float bf2f(short s) {
  __hip_bfloat16 b;
  __builtin_memcpy(&b, &s, 2);
  return __bfloat162float(b);
}
__device__ inline void split8(const float* v, short8_t* h, short8_t* l) {
#pragma unroll
  for (int i = 0; i < 8; i++) {
    short hh = f2bf(v[i]);
    (*h)[i] = hh;
    (*l)[i] = f2bf(v[i] - bf2f(hh));
  }
}

// ---- fused prep: embedding (hi/lo) + bucket histogram (dst>>6, 64B-padded) + weights ----
__global__ __launch_bounds__(256) void prep_k(
    const int* __restrict__ sid, const int* __restrict__ cid, const int* __restrict__ pid,
    const float* __restrict__ se, const float* __restrict__ ce, const float* __restrict__ pe,
    short* __restrict__ xh, short* __restrict__ xl,
    const int* __restrict__ dst, int* __restrict__ bcnt,
    const float* __restrict__ root1, const float* __restrict__ W1,
    const float* __restrict__ root2, const float* __restrict__ W2,
    short* __restrict__ w1h, short* __restrict__ w1l,
    short* __restrict__ w2h, short* __restrict__ w2l, int N, int E) {
  int i = blockIdx.x * 256 + threadIdx.x;
  if (i < N * 8) {  // embedding: one float4 slice per thread
    int n = i >> 3, cg = i & 7;
    const float4 a = *(const float4*)&se[sid[n] * EMB + cg * 4];
    const float4 b = *(const float4*)&ce[cid[n] * EMB + cg * 4];
    const float4 c = *(const float4*)&pe[pid[n] * EMB + cg * 4];
    float v[4];
    v[0] = a.x + b.x + c.x; v[1] = a.y + b.y + c.y;
    v[2] = a.z + b.z + c.z; v[3] = a.w + b.w + c.w;
    short4_t h, l;
#pragma unroll
    for (int j = 0; j < 4; j++) {
      short hh = f2bf(v[j]);
      h[j] = hh;
      l[j] = f2bf(v[j] - bf2f(hh));
    }
    *(short4_t*)&xh[(size_t)n * EMB + cg * 4] = h;
    *(short4_t*)&xl[(size_t)n * EMB + cg * 4] = l;
  }
  if (i < E) atomicAdd(&bcnt[(dst[i] >> 6) * 16], 1);  // one counter per 64B line
  if (i < 64 * 128) {  // layer-1 weights
    int k = i >> 6, n = i & 63;
    float v = (k < EMB) ? root1[k * 64 + n] : W1[(k - EMB) * 64 + n];
    short h = f2bf(v);
    w1h[n * 128 + k] = h;
    w1l[n * 128 + k] = f2bf(v - bf2f(h));
  }
  if (i < 64 * 256) {  // layer-2 weights
    int k = i >> 6, n = i & 63;
    float v = (k < HID) ? root2[k * 64 + n] : W2[(k - HID) * 64 + n];
    short h = f2bf(v);
    w2h[n * 256 + k] = h;
    w2l[n * 256 + k] = f2bf(v - bf2f(h));
  }
}

// single-block exclusive scan over NBk padded bucket counters -> boffs (compact) + bcur (padded)
__global__ __launch_bounds__(256) void bscan_k(const int* __restrict__ bcnt,
                                               int* __restrict__ boffs,
                                               int* __restrict__ bcur, int NBk) {
  __shared__ int tmp[256];
  __shared__ int carry_s;
  if (threadIdx.x == 0) carry_s = 0;
  __syncthreads();
  for (int base = 0; base < NBk; base += 256) {
    int i = base + threadIdx.x;
    int v = (i < NBk) ? bcnt[i * 16] : 0;
    tmp[threadIdx.x] = v;
    __syncthreads();
    for (int off = 1; off < 256; off <<= 1) {
      int u = (threadIdx.x >= off) ? tmp[threadIdx.x - off] : 0;
      __syncthreads();
      tmp[threadIdx.x] += u;
      __syncthreads();
    }
    int carry = carry_s;
    if (i < NBk) {
      int ex = carry + tmp[threadIdx.x] - v;
      boffs[i] = ex;
      bcur[i * 16] = ex;
    }
    __syncthreads();
    if (threadIdx.x == 0) carry_s = carry + tmp[255];
    __syncthreads();
  }
  if (threadIdx.x == 0) boffs[NBk] = carry_s;  // = E
}

// bucketize: append packed edge (dloc<<21 | et<<19 | src) at bucket cursor.
// Sequential-within-bucket writes fill L2 lines (no 64B write amplification).
__global__ __launch_bounds__(256) void bscatter_k(const int* __restrict__ src,
                                                  const int* __restrict__ dst,
                                                  const int* __restrict__ et,
                                                  int* __restrict__ bcur,
                                                  unsigned* __restrict__ pk, int E) {
  int e = blockIdx.x * 256 + threadIdx.x;
  if (e >= E) return;
  int d = dst[e];
  int pos = atomicAdd(&bcur[(d >> 6) * 16], 1);
  pk[pos] = ((unsigned)(d & 63) << 21) | ((unsigned)et[e] << 19) | (unsigned)src[e];
}

// ====== layer-1 fused: in-LDS CSR build + gather + phased MFMA (round-10 compute) ======
__global__ __launch_bounds__(256) void l1fused_k(
    const short* __restrict__ xh, const short* __restrict__ xl,
    const int* __restrict__ boffs, const unsigned* __restrict__ pk,
    const short* __restrict__ wth, const short* __restrict__ wtl,
    const float* __restrict__ bias, short* __restrict__ h1h, short* __restrict__ h1l, int N) {
  __shared__ __align__(16) short lws[64][16][8];   // 16 KB (one plane)
  __shared__ __align__(16) short gh_s[192][4][8];  // 12 KB
  __shared__ __align__(16) short gl_s[192][4][8];  // 12 KB
  __shared__ __align__(16) int4 mid_s[192];        //  3 KB (first-4 ids)
  __shared__ int cnt_s[192];
  __shared__ unsigned ovf_s[OVCAP];                //  4 KB (slot<<19 | src)
  __shared__ int ovfn_s;

  const int t = threadIdx.x;
  const int lane = t & 63, w = t >> 6;
  const int m_ = lane & 15, q = lane >> 4;
  const int n0b = blockIdx.x * 64;

  // ---- phase A: hi-plane weights -> LDS, self -> regs, init build state ----
  int node_c = n0b + w * 16 + m_;
  if (node_c >= N) node_c = N - 1;
  short8_t ah0 = *(const short8_t*)&xh[(size_t)node_c * EMB + q * 8];
  short8_t al0 = *(const short8_t*)&xl[(size_t)node_c * EMB + q * 8];
#pragma unroll
  for (int i = 0; i < 4; i++) {
    int chi = t + 256 * i;
    int row = chi >> 4, c = chi & 15;
    short8_t wv = *(const short8_t*)&wth[(size_t)row * 128 + c * 8];
    *(short8_t*)&lws[row][c ^ (row & 7)][0] = wv;
  }
  if (t < 192) cnt_s[t] = 0;
  if (t == 0) ovfn_s = 0;
  __syncthreads();

  // ---- phase B: in-LDS CSR build from bucketed packed edges (1 LDS atomic/edge) ----
  {
    const int beg = boffs[blockIdx.x], end = boffs[blockIdx.x + 1];
    for (int e = beg + t; e < end; e += 256) {
      unsigned p = pk[e];
      int srcn = (int)(p & 0x7FFFF);
      int slot = (int)((p >> 19) & 3) * 64 + (int)(p >> 21);
      int j = atomicAdd(&cnt_s[slot], 1);
      if (j < 4) ((int*)&mid_s[slot])[j] = srcn;
      else {
        int k2 = atomicAdd(&ovfn_s, 1);
        if (k2 < OVCAP) ovf_s[k2] = ((unsigned)slot << 19) | (unsigned)srcn;
      }
    }
  }
  __syncthreads();

  // ---- phase S: copy-shaped gather stage, 3 tasks/thread ----
  {
    int ovn = ovfn_s;
    if (ovn > OVCAP) ovn = OVCAP;
    int tslot[3], tq[3], tlen[3];
    int4 tid4[3];
#pragma unroll
    for (int k = 0; k < 3; k++) {
      int tau = t + 256 * k;
      tslot[k] = tau >> 2;
      tq[k] = tau & 3;
      tid4[k] = mid_s[tslot[k]];
      tlen[k] = cnt_s[tslot[k]];
    }
    short8_t v0[3], v1[3], v2[3], v3[3];
#pragma unroll
    for (int k = 0; k < 3; k++) {
      int nself = n0b + (tslot[k] & 63);
      if (nself >= N) nself = N - 1;
      int g0 = (0 < tlen[k]) ? tid4[k].x : nself;
      int g1 = (1 < tlen[k]) ? tid4[k].y : nself;
      int g2 = (2 < tlen[k]) ? tid4[k].z : nself;
      int g3 = (3 < tlen[k]) ? tid4[k].w : nself;
      size_t co = (size_t)tq[k] * 8;
      v0[k] = *(const short8_t*)&xh[(size_t)g0 * EMB + co];
      v1[k] = *(const short8_t*)&xh[(size_t)g1 * EMB + co];
      v2[k] = *(const short8_t*)&xh[(size_t)g2 * EMB + co];
      v3[k] = *(const short8_t*)&xh[(size_t)g3 * EMB + co];
    }
#pragma unroll
    for (int k = 0; k < 3; k++) {
      float a[8];
      float k0 = (0 < tlen[k]) ? 1.f : 0.f;
      float k1 = (1 < tlen[k]) ? 1.f : 0.f;
      float k2 = (2 < tlen[k]) ? 1.f : 0.f;
      float k3 = (3 < tlen[k]) ? 1.f : 0.f;
#pragma unroll
      for (int i = 0; i < 8; i++)
        a[i] = k0 * bf2f(v0[k][i]) + k1 * bf2f(v1[k][i]) + k2 * bf2f(v2[k][i]) +
               k3 * bf2f(v3[k][i]);
      // rare tail: scan tiny LDS overflow list (~7 entries/bucket)
      for (int k3_ = 0; k3_ < ovn; k3_++) {
        unsigned ov = ovf_s[k3_];
        if ((int)(ov >> 19) == tslot[k]) {
          short8_t u = *(const short8_t*)&xh[(size_t)(ov & 0x7FFFF) * EMB + tq[k] * 8];
#pragma unroll
          for (int i = 0; i < 8; i++) a[i] += bf2f(u[i]);
        }
      }
      float inv = 1.f / fmaxf((float)tlen[k], 1.f);
#pragma unroll
      for (int i = 0; i < 8; i++) a[i] *= inv;
      short8_t hi, lo;
      split8(a, &hi, &lo);
      int qs = tq[k] ^ (tslot[k] & 3);
      *(short8_t*)&gh_s[tslot[k]][qs][0] = hi;
      *(short8_t*)&gl_s[tslot[k]][qs][0] = lo;
    }
  }
  __syncthreads();

  // ---- phase Ca: hi-plane MFMAs; latch a-fragments in regs ----
  f32x4 acc[4];
#pragma unroll
  for (int i = 0; i < 4; i++) acc[i] = (f32x4){0.f, 0.f, 0.f, 0.f};
  short8_t ahv[4], alv[4];
#pragma unroll
  for (int g = 0; g < 4; g++) {
    if (g == 0) {
      ahv[0] = ah0;
      alv[0] = al0;
    } else {
      int slot = (g - 1) * 64 + w * 16 + m_;
      int qs = q ^ (slot & 3);
      ahv[g] = *(const short8_t*)&gh_s[slot][qs][0];
      alv[g] = *(const short8_t*)&gl_s[slot][qs][0];
    }
#pragma unroll
    for (int tt = 0; tt < 4; tt++) {
      int row = 16 * tt + m_;
      int cs = (g * 4 + q) ^ (row & 7);
      short8_t bh = *(const short8_t*)&lws[row][cs][0];
      acc[tt] = __builtin_amdgcn_mfma_f32_16x16x32_bf16(ahv[g], bh, acc[tt], 0, 0, 0);
      acc[tt] = __builtin_amdgcn_mfma_f32_16x16x32_bf16(alv[g], bh, acc[tt], 0, 0, 0);
    }
  }
  __syncthreads();

  // ---- phase St: stage lo-plane weights ----
#pragma unroll
  for (int i = 0; i < 4; i++) {
    int chi = t + 256 * i;
    int row = chi >> 4, c = chi & 15;
    short8_t wv = *(const short8_t*)&wtl[(size_t)row * 128 + c * 8];
    *(short8_t*)&lws[row][c ^ (row & 7)][0] = wv;
  }
  __syncthreads();

  // ---- phase Cb: lo-plane MFMAs ----
#pragma unroll
  for (int g = 0; g < 4; g++) {
#pragma unroll
    for (int tt = 0; tt < 4; tt++) {
      int row = 16 * tt + m_;
      int cs = (g * 4 + q) ^ (row & 7);
      short8_t bl = *(const short8_t*)&lws[row][cs][0];
      acc[tt] = __builtin_amdgcn_mfma_f32_16x16x32_bf16(ahv[g], bl, acc[tt], 0, 0, 0);
    }
  }
  // epilogue: bias + relu + hi/lo split store
#pragma unroll
  for (int tt = 0; tt < 4; tt++) {
    float bia = bias[16 * tt + m_];
#pragma unroll
    for (int reg = 0; reg < 4; reg++) {
      int node = n0b + w * 16 + q * 4 + reg;
      if (node < N) {
        float val = fmaxf(acc[tt][reg] + bia, 0.f);
        short hh = f2bf(val);
        h1h[(size_t)node * HID + 16 * tt + m_] = hh;
        h1l[(size_t)node * HID + 16 * tt + m_] = f2bf(val - bf2f(hh));
      }
    }
  }
}

// ====== layer-2 fused: in-LDS CSR build + per-K-half gather + phased MFMA ======
__global__ __launch_bounds__(256) void l2fused_k(
    const short* __restrict__ h1h, const short* __restrict__ h1l,
    const int* __restrict__ boffs, const unsigned* __restrict__ pk,
    const short* __restrict__ wth, const short* __restrict__ wtl,
    const float* __restrict__ bias, const float* __restrict__ linW,
    const int* __restrict__ batch, float* __restrict__ gs, float* __restrict__ gc, int N) {
  __shared__ __align__(16) short lws[64][16][8];   // 16 KB (one plane, one K-half)
  __shared__ __align__(16) short gh_s[192][4][8];  // 12 KB
  __shared__ __align__(16) short gl_s[192][4][8];  // 12 KB
  __shared__ __align__(16) int4 mid_s[192];        //  3 KB
  __shared__ int cnt_s[192];
  __shared__ unsigned ovf_s[OVCAP];                //  4 KB
  __shared__ int ovfn_s;

  const int t = threadIdx.x;
  const int lane = t & 63, w = t >> 6;
  const int m_ = lane & 15, q = lane >> 4;
  const int n0b = blockIdx.x * 64;

  // ---- phase A: self -> regs; hi-weights(s0) -> LDS; init build state ----
  int node_c = n0b + w * 16 + m_;
  if (node_c >= N) node_c = N - 1;
  short8_t ash[2], asl[2];
#pragma unroll
  for (int s_ = 0; s_ < 2; s_++) {
    ash[s_] = *(const short8_t*)&h1h[(size_t)node_c * HID + s_ * 32 + q * 8];
    asl[s_] = *(const short8_t*)&h1l[(size_t)node_c * HID + s_ * 32 + q * 8];
  }
#pragma unroll
  for (int i = 0; i < 4; i++) {
    int chi = t + 256 * i;
    int row = chi >> 4, c = chi & 15;
    int g = c >> 2, qq = c & 3;
    short8_t wv = *(const short8_t*)&wth[(size_t)row * 256 + g * 64 + 0 * 32 + qq * 8];
    *(short8_t*)&lws[row][c ^ (row & 7)][0] = wv;
  }
  if (t < 192) cnt_s[t] = 0;
  if (t == 0) ovfn_s = 0;
  __syncthreads();

  // ---- phase B: in-LDS CSR build (1 LDS atomic/edge) ----
  {
    const int beg = boffs[blockIdx.x], end = boffs[blockIdx.x + 1];
    for (int e = beg + t; e < end; e += 256) {
      unsigned p = pk[e];
      int srcn = (int)(p & 0x7FFFF);
      int slot = (int)((p >> 19) & 3) * 64 + (int)(p >> 21);
      int j = atomicAdd(&cnt_s[slot], 1);
      if (j < 4) ((int*)&mid_s[slot])[j] = srcn;
      else {
        int k2 = atomicAdd(&ovfn_s, 1);
        if (k2 < OVCAP) ovf_s[k2] = ((unsigned)slot << 19) | (unsigned)srcn;
      }
    }
  }
  __syncthreads();

  f32x4 acc[4];
#pragma unroll
  for (int i = 0; i < 4; i++) acc[i] = (f32x4){0.f, 0.f, 0.f, 0.f};

  int ovn = ovfn_s;
  if (ovn > OVCAP) ovn = OVCAP;

#pragma unroll
  for (int s_ = 0; s_ < 2; s_++) {
    // ---- phase S(s_): gather; on s_=1 also re-stage hi-weights(s1) ----
    if (s_ == 1) {
#pragma unroll
      for (int i = 0; i < 4; i++) {
        int chi = t + 256 * i;
        int row = chi >> 4, c = chi & 15;
        int g = c >> 2, q2 = c & 3;
        short8_t wv = *(const short8_t*)&wth[(size_t)row * 256 + g * 64 + 32 + q2 * 8];
        *(short8_t*)&lws[row][c ^ (row & 7)][0] = wv;
      }
    }
    int tslot[3], tq[3], tlen[3];
    int4 tid4[3];
#pragma unroll
    for (int k = 0; k < 3; k++) {
      int tau = t + 256 * k;
      tslot[k] = tau >> 2;
      tq[k] = tau & 3;
      tid4[k] = mid_s[tslot[k]];
      tlen[k] = cnt_s[tslot[k]];
    }
    short8_t v0[3], v1[3], v2[3], v3[3];
#pragma unroll
    for (int k = 0; k < 3; k++) {
      int nself = n0b + (tslot[k] & 63);
      if (nself >= N) nself = N - 1;
      int g0 = (0 < tlen[k]) ? tid4[k].x : nself;
      int g1 = (1 < tlen[k]) ? tid4[k].y : nself;
      int g2 = (2 < tlen[k]) ? tid4[k].z : nself;
      int g3 = (3 < tlen[k]) ? tid4[k].w : nself;
      size_t co = (size_t)s_ * 32 + tq[k] * 8;
      v0[k] = *(const short8_t*)&h1h[(size_t)g0 * HID + co];
      v1[k] = *(const short8_t*)&h1h[(size_t)g1 * HID + co];
      v2[k] = *(const short8_t*)&h1h[(size_t)g2 * HID + co];
      v3[k] = *(const short8_t*)&h1h[(size_t)g3 * HID + co];
    }
#pragma unroll
    for (int k = 0; k < 3; k++) {
      float a[8];
      float k0 = (0 < tlen[k]) ? 1.f : 0.f;
      float k1 = (1 < tlen[k]) ? 1.f : 0.f;
      float k2 = (2 < tlen[k]) ? 1.f : 0.f;
      float k3 = (3 < tlen[k]) ? 1.f : 0.f;
#pragma unroll
      for (int i = 0; i < 8; i++)
        a[i] = k0 * bf2f(v0[k][i]) + k1 * bf2f(v1[k][i]) + k2 * bf2f(v2[k][i]) +
               k3 * bf2f(v3[k][i]);
      // rare tail: scan tiny LDS overflow list
      for (int k3_ = 0; k3_ < ovn; k3_++) {
        unsigned ov = ovf_s[k3_];
        if ((int)(ov >> 19) == tslot[k]) {
          short8_t u = *(const short8_t*)&h1h[(size_t)(ov & 0x7FFFF) * HID + s_ * 32 +
                                              tq[k] * 8];
#pragma unroll
          for (int i = 0; i < 8; i++) a[i] += bf2f(u[i]);
        }
      }
      float inv = 1.f / fmaxf((float)tlen[k], 1.f);
#pragma unroll
      for (int i = 0; i < 8; i++) a[i] *= inv;
      short8_t hi, lo;
      split8(a, &hi, &lo);
      int qs = tq[k] ^ (tslot[k] & 3);
      *(short8_t*)&gh_s[tslot[k]][qs][0] = hi;
      *(short8_t*)&gl_s[tslot[k]][qs][0] = lo;
    }
    __syncthreads();

    // ---- phase Ca(s_): hi-plane MFMAs; latch a-fragments ----
    short8_t ahv[4], alv[4];
#pragma unroll
    for (int g = 0; g < 4; g++) {
      if (g == 0) {
        ahv[0] = ash[s_];
        alv[0] = asl[s_];
      } else {
        int slot = (g - 1) * 64 + w * 16 + m_;
        int qs = q ^ (slot & 3);
        ahv[g] = *(const short8_t*)&gh_s[slot][qs][0];
        alv[g] = *(const short8_t*)&gl_s[slot][qs][0];
      }
#pragma unroll
      for (int tt = 0; tt < 4; tt++) {
        int row = 16 * tt + m_;
        int cs = (g * 4 + q) ^ (row & 7);
        short8_t bh = *(const short8_t*)&lws[row][cs][0];
        acc[tt] = __builtin_amdgcn_mfma_f32_16x16x32_bf16(ahv[g], bh, acc[tt], 0, 0, 0);
        acc[tt] = __builtin_amdgcn_mfma_f32_16x16x32_bf16(alv[g], bh, acc[tt], 0, 0, 0);
      }
    }
    __syncthreads();

    // ---- phase St(s_): stage lo-plane weights for this K-half ----
#pragma unroll
    for (int i = 0; i < 4; i++) {
      int chi = t + 256 * i;
      int row = chi >> 4, c = chi & 15;
      int g = c >> 2, q2 = c & 3;
      short8_t wv = *(const short8_t*)&wtl[(size_t)row * 256 + g * 64 + s_ * 32 + q2 * 8];
      *(short8_t*)&lws[row][c ^ (row & 7)][0] = wv;
    }
    __syncthreads();

    // ---- phase Cb(s_): lo-plane MFMAs (a-fragments from regs) ----
#pragma unroll
    for (int g = 0; g < 4; g++) {
#pragma unroll
      for (int tt = 0; tt < 4; tt++) {
        int row = 16 * tt + m_;
        int cs = (g * 4 + q) ^ (row & 7);
        short8_t bl = *(const short8_t*)&lws[row][cs][0];
        acc[tt] = __builtin_amdgcn_mfma_f32_16x16x32_bf16(ahv[g], bl, acc[tt], 0, 0, 0);
      }
    }
    if (s_ == 0) __syncthreads();  // protect gh/gl + lws before S1 overwrites
  }

  // ---- pooled epilogue ----
  float bia[4], lw0[4], lw1[4];
#pragma unroll
  for (int tt = 0; tt < 4; tt++) {
    int col = 16 * tt + m_;
    bia[tt] = bias[col];
    lw0[tt] = linW[col * 2 + 0];
    lw1[tt] = linW[col * 2 + 1];
  }
#pragma unroll
  for (int reg = 0; reg < 4; reg++) {
    int node = n0b + w * 16 + q * 4 + reg;
    float p0 = 0.f, p1 = 0.f;
#pragma unroll
    for (int tt = 0; tt < 4; tt++) {
      float v = fmaxf(acc[tt][reg] + bia[tt], 0.f);
      p0 += v * lw0[tt];
      p1 += v * lw1[tt];
    }
#pragma unroll
    for (int o = 1; o < 16; o <<= 1) {
      p0 += __shfl_xor(p0, o, 64);
      p1 += __shfl_xor(p1, o, 64);
    }
    if (m_ == 0 && node < N) {
      int g = batch[node];
      atomicAdd(&gs[g * 2 + 0], p0);
      atomicAdd(&gs[g * 2 + 1], p1);
      atomicAdd(&gc[g], 1.0f);
    }
  }
}

__global__ __launch_bounds__(256) void final_k(const float* __restrict__ gs,
                                               const float* __restrict__ gc,
                                               const float* __restrict__ linb,
                                               float* __restrict__ out, int G) {
  int i = blockIdx.x * 256 + threadIdx.x;
  if (i >= G * 2) return;
  int g = i >> 1, o = i & 1;
  out[i] = gs[i] / fmaxf(gc[g], 1.0f) + linb[o];
}

extern "C" void kernel_launch(void* const* d_in, const int* in_sizes, int n_in,
                              void* d_out, int out_size, void* d_ws, size_t ws_size,
                              hipStream_t stream) {
  const int* sid = (const int*)d_in[0];
  const int* cid = (const int*)d_in[1];
  const int* pid = (const int*)d_in[2];
  const int* ei = (const int*)d_in[3];
  const int* et = (const int*)d_in[4];
  const int* batch = (const int*)d_in[5];
  const float* se = (const float*)d_in[7];
  const float* ce = (const float*)d_in[8];
  const float* pe = (const float*)d_in[9];
  const float* W1 = (const float*)d_in[10];
  const float* root1 = (const float*)d_in[11];
  const float* b1 = (const float*)d_in[12];
  const float* W2 = (const float*)d_in[13];
  const float* root2 = (const float*)d_in[14];
  const float* b2 = (const float*)d_in[15];
  const float* linW = (const float*)d_in[16];
  const float* linb = (const float*)d_in[17];
  float* out = (float*)d_out;

  const int N = in_sizes[0];
  const int E = in_sizes[4];
  const int G = out_size / 2;
  const int* src = ei;
  const int* dst = ei + E;
  const int NBk = (N + 63) / 64;     // buckets == fused-layer blocks
  const int NBa = (NBk + 15) & ~15;  // aligned allocation

  // ---- workspace layout (16B-aligned blocks) ----
  char* w = (char*)d_ws;
  short* h1h = (short*)w;  w += (size_t)N * HID * sizeof(short);
  short* h1l = (short*)w;  w += (size_t)N * HID * sizeof(short);
  short* xh = (short*)w;   w += (size_t)N * EMB * sizeof(short);
  short* xl = (short*)w;   w += (size_t)N * EMB * sizeof(short);
  float* gs = (float*)w;   w += (size_t)G * 2 * sizeof(float);
  float* gc = (float*)w;   w += (size_t)G * sizeof(float);
  int* bcnt = (int*)w;     w += (size_t)NBa * 16 * sizeof(int);  // 64B-padded counters
  int* bcur = (int*)w;     w += (size_t)NBa * 16 * sizeof(int);
  int* boffs = (int*)w;    w += (size_t)(NBa + 16) * sizeof(int);
  unsigned* pk = (unsigned*)w; w += (size_t)E * sizeof(unsigned);
  short* w1h = (short*)w;  w += (size_t)64 * 128 * sizeof(short);
  short* w1l = (short*)w;  w += (size_t)64 * 128 * sizeof(short);
  short* w2h = (short*)w;  w += (size_t)64 * 256 * sizeof(short);
  short* w2l = (short*)w;  w += (size_t)64 * 256 * sizeof(short);
  if ((size_t)(w - (char*)d_ws) > ws_size) return;  // fail loudly, no OOB

  hipMemsetAsync(bcnt, 0, (size_t)NBa * 16 * sizeof(int), stream);
  hipMemsetAsync(gs, 0, (size_t)G * 3 * sizeof(float), stream);

  int prep_n = N * 8;  // covers E (1.5M) and weight ranges too for this problem size
  if (prep_n < E) prep_n = E;
  if (prep_n < 64 * 256) prep_n = 64 * 256;
  prep_k<<<(prep_n + 255) / 256, 256, 0, stream>>>(sid, cid, pid, se, ce, pe, xh, xl, dst,
                                                   bcnt, root1, W1, root2, W2, w1h, w1l, w2h,
                                                   w2l, N, E);
  bscan_k<<<1, 256, 0, stream>>>(bcnt, boffs, bcur, NBk);
  bscatter_k<<<(E + 255) / 256, 256, 0, stream>>>(src, dst, et, bcur, pk, E);

  l1fused_k<<<NBk, 256, 0, stream>>>(xh, xl, boffs, pk, w1h, w1l, b1, h1h, h1l, N);
  l2fused_k<<<NBk, 256, 0, stream>>>(h1h, h1l, boffs, pk, w2h, w2l, b2, linW, batch, gs, gc,
                                     N);
  final_k<<<(G * 2 + 255) / 256, 256, 0, stream>>>(gs, gc, linb, out, G);
}

// Round 14
// 387.004 us; speedup vs baseline: 2.9438x; 1.2112x over previous
//
#include <hip/hip_runtime.h>
#include <hip/hip_bf16.h>

#define NREL 3
#define EMB 32
#define HID 64
#define OVCAP 1024
#define BCAP 1024  // per-bucket pk capacity; buckets are Poisson(~320), P(>1024)~e^-487

typedef __attribute__((ext_vector_type(8))) short short8_t;
typedef __attribute__((ext_vector_type(4))) short short4_t;
typedef __attribute__((ext_vector_type(4))) float f32x4;

__device__ inline short f2bf(float v) {
  __hip_bfloat16 b = __float2bfloat16(v);
  short s;
  __builtin_memcpy(&s, &b, 2);
  return s;
}
__device__ inline float bf2f(short s) {
  __hip_bfloat16 b;
  __builtin_memcpy(&b, &s, 2);
  return __bfloat162float(b);
}
__device__ inline void split8(const float* v, short8_t* h, short8_t* l) {
#pragma unroll
  for (int i = 0; i < 8; i++) {
    short hh = f2bf(v[i]);
    (*h)[i] = hh;
    (*l)[i] = f2bf(v[i] - bf2f(hh));
  }
}

// ---- fused prep: embedding (hi/lo) + DIRECT bucket append (no histogram/scan/scatter) ----
__global__ __launch_bounds__(256) void prep_k(
    const int* __restrict__ sid, const int* __restrict__ cid, const int* __restrict__ pid,
    const float* __restrict__ se, const float* __restrict__ ce, const float* __restrict__ pe,
    short* __restrict__ xh, short* __restrict__ xl,
    const int* __restrict__ src, const int* __restrict__ dst, const int* __restrict__ et,
    int* __restrict__ bcur, unsigned* __restrict__ pk,
    const float* __restrict__ root1, const float* __restrict__ W1,
    const float* __restrict__ root2, const float* __restrict__ W2,
    short* __restrict__ w1h, short* __restrict__ w1l,
    short* __restrict__ w2h, short* __restrict__ w2l, int N, int E) {
  int i = blockIdx.x * 256 + threadIdx.x;
  if (i < N * 8) {  // embedding: one float4 slice per thread
    int n = i >> 3, cg = i & 7;
    const float4 a = *(const float4*)&se[sid[n] * EMB + cg * 4];
    const float4 b = *(const float4*)&ce[cid[n] * EMB + cg * 4];
    const float4 c = *(const float4*)&pe[pid[n] * EMB + cg * 4];
    float v[4];
    v[0] = a.x + b.x + c.x; v[1] = a.y + b.y + c.y;
    v[2] = a.z + b.z + c.z; v[3] = a.w + b.w + c.w;
    short4_t h, l;
#pragma unroll
    for (int j = 0; j < 4; j++) {
      short hh = f2bf(v[j]);
      h[j] = hh;
      l[j] = f2bf(v[j] - bf2f(hh));
    }
    *(short4_t*)&xh[(size_t)n * EMB + cg * 4] = h;
    *(short4_t*)&xl[(size_t)n * EMB + cg * 4] = l;
  }
  if (i < E) {  // direct bucket append: histogram atomic IS the append atomic
    int d = dst[i];
    int b = d >> 6;
    int j = atomicAdd(&bcur[b * 16], 1);  // one counter per 64B line
    if (j < BCAP)
      pk[(size_t)b * BCAP + j] =
          ((unsigned)(d & 63) << 21) | ((unsigned)et[i] << 19) | (unsigned)src[i];
  }
  if (i < 64 * 128) {  // layer-1 weights
    int k = i >> 6, n = i & 63;
    float v = (k < EMB) ? root1[k * 64 + n] : W1[(k - EMB) * 64 + n];
    short h = f2bf(v);
    w1h[n * 128 + k] = h;
    w1l[n * 128 + k] = f2bf(v - bf2f(h));
  }
  if (i < 64 * 256) {  // layer-2 weights
    int k = i >> 6, n = i & 63;
    float v = (k < HID) ? root2[k * 64 + n] : W2[(k - HID) * 64 + n];
    short h = f2bf(v);
    w2h[n * 256 + k] = h;
    w2l[n * 256 + k] = f2bf(v - bf2f(h));
  }
}

// ====== layer-1 fused: in-LDS CSR build + gather + phased MFMA ======
__global__ __launch_bounds__(256) void l1fused_k(
    const short* __restrict__ xh, const short* __restrict__ xl,
    const int* __restrict__ bcur, const unsigned* __restrict__ pk,
    const short* __restrict__ wth, const short* __restrict__ wtl,
    const float* __restrict__ bias, short* __restrict__ h1h, short* __restrict__ h1l, int N) {
  __shared__ __align__(16) short lws[64][16][8];   // 16 KB (one plane)
  __shared__ __align__(16) short gh_s[192][4][8];  // 12 KB
  __shared__ __align__(16) short gl_s[192][4][8];  // 12 KB
  __shared__ __align__(16) int4 mid_s[192];        //  3 KB (first-4 ids)
  __shared__ int cnt_s[192];
  __shared__ unsigned ovf_s[OVCAP];                //  4 KB (slot<<19 | src)
  __shared__ int ovfn_s;

  const int t = threadIdx.x;
  const int lane = t & 63, w = t >> 6;
  const int m_ = lane & 15, q = lane >> 4;
  const int n0b = blockIdx.x * 64;

  // ---- phase A: hi-plane weights -> LDS, self -> regs, init build state ----
  int node_c = n0b + w * 16 + m_;
  if (node_c >= N) node_c = N - 1;
  short8_t ah0 = *(const short8_t*)&xh[(size_t)node_c * EMB + q * 8];
  short8_t al0 = *(const short8_t*)&xl[(size_t)node_c * EMB + q * 8];
#pragma unroll
  for (int i = 0; i < 4; i++) {
    int chi = t + 256 * i;
    int row = chi >> 4, c = chi & 15;
    short8_t wv = *(const short8_t*)&wth[(size_t)row * 128 + c * 8];
    *(short8_t*)&lws[row][c ^ (row & 7)][0] = wv;
  }
  if (t < 192) cnt_s[t] = 0;
  if (t == 0) ovfn_s = 0;
  __syncthreads();

  // ---- phase B: in-LDS CSR build from fixed-capacity bucket (1 LDS atomic/edge) ----
  {
    int ne = bcur[blockIdx.x * 16];
    if (ne > BCAP) ne = BCAP;
    const size_t base = (size_t)blockIdx.x * BCAP;
    for (int e = t; e < ne; e += 256) {
      unsigned p = pk[base + e];
      int srcn = (int)(p & 0x7FFFF);
      int slot = (int)((p >> 19) & 3) * 64 + (int)(p >> 21);
      int j = atomicAdd(&cnt_s[slot], 1);
      if (j < 4) ((int*)&mid_s[slot])[j] = srcn;
      else {
        int k2 = atomicAdd(&ovfn_s, 1);
        if (k2 < OVCAP) ovf_s[k2] = ((unsigned)slot << 19) | (unsigned)srcn;
      }
    }
  }
  __syncthreads();

  // ---- phase S: copy-shaped gather stage, 3 tasks/thread ----
  {
    int ovn = ovfn_s;
    if (ovn > OVCAP) ovn = OVCAP;
    int tslot[3], tq[3], tlen[3];
    int4 tid4[3];
#pragma unroll
    for (int k = 0; k < 3; k++) {
      int tau = t + 256 * k;
      tslot[k] = tau >> 2;
      tq[k] = tau & 3;
      tid4[k] = mid_s[tslot[k]];
      tlen[k] = cnt_s[tslot[k]];
    }
    short8_t v0[3], v1[3], v2[3], v3[3];
#pragma unroll
    for (int k = 0; k < 3; k++) {
      int nself = n0b + (tslot[k] & 63);
      if (nself >= N) nself = N - 1;
      int g0 = (0 < tlen[k]) ? tid4[k].x : nself;
      int g1 = (1 < tlen[k]) ? tid4[k].y : nself;
      int g2 = (2 < tlen[k]) ? tid4[k].z : nself;
      int g3 = (3 < tlen[k]) ? tid4[k].w : nself;
      size_t co = (size_t)tq[k] * 8;
      v0[k] = *(const short8_t*)&xh[(size_t)g0 * EMB + co];
      v1[k] = *(const short8_t*)&xh[(size_t)g1 * EMB + co];
      v2[k] = *(const short8_t*)&xh[(size_t)g2 * EMB + co];
      v3[k] = *(const short8_t*)&xh[(size_t)g3 * EMB + co];
    }
#pragma unroll
    for (int k = 0; k < 3; k++) {
      float a[8];
      float k0 = (0 < tlen[k]) ? 1.f : 0.f;
      float k1 = (1 < tlen[k]) ? 1.f : 0.f;
      float k2 = (2 < tlen[k]) ? 1.f : 0.f;
      float k3 = (3 < tlen[k]) ? 1.f : 0.f;
#pragma unroll
      for (int i = 0; i < 8; i++)
        a[i] = k0 * bf2f(v0[k][i]) + k1 * bf2f(v1[k][i]) + k2 * bf2f(v2[k][i]) +
               k3 * bf2f(v3[k][i]);
      // rare tail: scan tiny LDS overflow list (~7 entries/bucket)
      for (int k3_ = 0; k3_ < ovn; k3_++) {
        unsigned ov = ovf_s[k3_];
        if ((int)(ov >> 19) == tslot[k]) {
          short8_t u = *(const short8_t*)&xh[(size_t)(ov & 0x7FFFF) * EMB + tq[k] * 8];
#pragma unroll
          for (int i = 0; i < 8; i++) a[i] += bf2f(u[i]);
        }
      }
      float inv = 1.f / fmaxf((float)tlen[k], 1.f);
#pragma unroll
      for (int i = 0; i < 8; i++) a[i] *= inv;
      short8_t hi, lo;
      split8(a, &hi, &lo);
      int qs = tq[k] ^ (tslot[k] & 3);
      *(short8_t*)&gh_s[tslot[k]][qs][0] = hi;
      *(short8_t*)&gl_s[tslot[k]][qs][0] = lo;
    }
  }
  __syncthreads();

  // ---- phase Ca: hi-plane MFMAs; latch a-fragments in regs ----
  f32x4 acc[4];
#pragma unroll
  for (int i = 0; i < 4; i++) acc[i] = (f32x4){0.f, 0.f, 0.f, 0.f};
  short8_t ahv[4], alv[4];
#pragma unroll
  for (int g = 0; g < 4; g++) {
    if (g == 0) {
      ahv[0] = ah0;
      alv[0] = al0;
    } else {
      int slot = (g - 1) * 64 + w * 16 + m_;
      int qs = q ^ (slot & 3);
      ahv[g] = *(const short8_t*)&gh_s[slot][qs][0];
      alv[g] = *(const short8_t*)&gl_s[slot][qs][0];
    }
#pragma unroll
    for (int tt = 0; tt < 4; tt++) {
      int row = 16 * tt + m_;
      int cs = (g * 4 + q) ^ (row & 7);
      short8_t bh = *(const short8_t*)&lws[row][cs][0];
      acc[tt] = __builtin_amdgcn_mfma_f32_16x16x32_bf16(ahv[g], bh, acc[tt], 0, 0, 0);
      acc[tt] = __builtin_amdgcn_mfma_f32_16x16x32_bf16(alv[g], bh, acc[tt], 0, 0, 0);
    }
  }
  __syncthreads();

  // ---- phase St: stage lo-plane weights ----
#pragma unroll
  for (int i = 0; i < 4; i++) {
    int chi = t + 256 * i;
    int row = chi >> 4, c = chi & 15;
    short8_t wv = *(const short8_t*)&wtl[(size_t)row * 128 + c * 8];
    *(short8_t*)&lws[row][c ^ (row & 7)][0] = wv;
  }
  __syncthreads();

  // ---- phase Cb: lo-plane MFMAs ----
#pragma unroll
  for (int g = 0; g < 4; g++) {
#pragma unroll
    for (int tt = 0; tt < 4; tt++) {
      int row = 16 * tt + m_;
      int cs = (g * 4 + q) ^ (row & 7);
      short8_t bl = *(const short8_t*)&lws[row][cs][0];
      acc[tt] = __builtin_amdgcn_mfma_f32_16x16x32_bf16(ahv[g], bl, acc[tt], 0, 0, 0);
    }
  }
  // epilogue: bias + relu + hi/lo split store
#pragma unroll
  for (int tt = 0; tt < 4; tt++) {
    float bia = bias[16 * tt + m_];
#pragma unroll
    for (int reg = 0; reg < 4; reg++) {
      int node = n0b + w * 16 + q * 4 + reg;
      if (node < N) {
        float val = fmaxf(acc[tt][reg] + bia, 0.f);
        short hh = f2bf(val);
        h1h[(size_t)node * HID + 16 * tt + m_] = hh;
        h1l[(size_t)node * HID + 16 * tt + m_] = f2bf(val - bf2f(hh));
      }
    }
  }
}

// ====== layer-2 fused: in-LDS CSR build + per-K-half gather + phased MFMA ======
__global__ __launch_bounds__(256) void l2fused_k(
    const short* __restrict__ h1h, const short* __restrict__ h1l,
    const int* __restrict__ bcur, const unsigned* __restrict__ pk,
    const short* __restrict__ wth, const short* __restrict__ wtl,
    const float* __restrict__ bias, const float* __restrict__ linW,
    const int* __restrict__ batch, float* __restrict__ gs, float* __restrict__ gc, int N) {
  __shared__ __align__(16) short lws[64][16][8];   // 16 KB (one plane, one K-half)
  __shared__ __align__(16) short gh_s[192][4][8];  // 12 KB
  __shared__ __align__(16) short gl_s[192][4][8];  // 12 KB
  __shared__ __align__(16) int4 mid_s[192];        //  3 KB
  __shared__ int cnt_s[192];
  __shared__ unsigned ovf_s[OVCAP];                //  4 KB
  __shared__ int ovfn_s;

  const int t = threadIdx.x;
  const int lane = t & 63, w = t >> 6;
  const int m_ = lane & 15, q = lane >> 4;
  const int n0b = blockIdx.x * 64;

  // ---- phase A: self -> regs; hi-weights(s0) -> LDS; init build state ----
  int node_c = n0b + w * 16 + m_;
  if (node_c >= N) node_c = N - 1;
  short8_t ash[2], asl[2];
#pragma unroll
  for (int s_ = 0; s_ < 2; s_++) {
    ash[s_] = *(const short8_t*)&h1h[(size_t)node_c * HID + s_ * 32 + q * 8];
    asl[s_] = *(const short8_t*)&h1l[(size_t)node_c * HID + s_ * 32 + q * 8];
  }
#pragma unroll
  for (int i = 0; i < 4; i++) {
    int chi = t + 256 * i;
    int row = chi >> 4, c = chi & 15;
    int g = c >> 2, qq = c & 3;
    short8_t wv = *(const short8_t*)&wth[(size_t)row * 256 + g * 64 + 0 * 32 + qq * 8];
    *(short8_t*)&lws[row][c ^ (row & 7)][0] = wv;
  }
  if (t < 192) cnt_s[t] = 0;
  if (t == 0) ovfn_s = 0;
  __syncthreads();

  // ---- phase B: in-LDS CSR build (1 LDS atomic/edge) ----
  {
    int ne = bcur[blockIdx.x * 16];
    if (ne > BCAP) ne = BCAP;
    const size_t base = (size_t)blockIdx.x * BCAP;
    for (int e = t; e < ne; e += 256) {
      unsigned p = pk[base + e];
      int srcn = (int)(p & 0x7FFFF);
      int slot = (int)((p >> 19) & 3) * 64 + (int)(p >> 21);
      int j = atomicAdd(&cnt_s[slot], 1);
      if (j < 4) ((int*)&mid_s[slot])[j] = srcn;
      else {
        int k2 = atomicAdd(&ovfn_s, 1);
        if (k2 < OVCAP) ovf_s[k2] = ((unsigned)slot << 19) | (unsigned)srcn;
      }
    }
  }
  __syncthreads();

  f32x4 acc[4];
#pragma unroll
  for (int i = 0; i < 4; i++) acc[i] = (f32x4){0.f, 0.f, 0.f, 0.f};

  int ovn = ovfn_s;
  if (ovn > OVCAP) ovn = OVCAP;

#pragma unroll
  for (int s_ = 0; s_ < 2; s_++) {
    // ---- phase S(s_): gather; on s_=1 also re-stage hi-weights(s1) ----
    if (s_ == 1) {
#pragma unroll
      for (int i = 0; i < 4; i++) {
        int chi = t + 256 * i;
        int row = chi >> 4, c = chi & 15;
        int g = c >> 2, q2 = c & 3;
        short8_t wv = *(const short8_t*)&wth[(size_t)row * 256 + g * 64 + 32 + q2 * 8];
        *(short8_t*)&lws[row][c ^ (row & 7)][0] = wv;
      }
    }
    int tslot[3], tq[3], tlen[3];
    int4 tid4[3];
#pragma unroll
    for (int k = 0; k < 3; k++) {
      int tau = t + 256 * k;
      tslot[k] = tau >> 2;
      tq[k] = tau & 3;
      tid4[k] = mid_s[tslot[k]];
      tlen[k] = cnt_s[tslot[k]];
    }
    short8_t v0[3], v1[3], v2[3], v3[3];
#pragma unroll
    for (int k = 0; k < 3; k++) {
      int nself = n0b + (tslot[k] & 63);
      if (nself >= N) nself = N - 1;
      int g0 = (0 < tlen[k]) ? tid4[k].x : nself;
      int g1 = (1 < tlen[k]) ? tid4[k].y : nself;
      int g2 = (2 < tlen[k]) ? tid4[k].z : nself;
      int g3 = (3 < tlen[k]) ? tid4[k].w : nself;
      size_t co = (size_t)s_ * 32 + tq[k] * 8;
      v0[k] = *(const short8_t*)&h1h[(size_t)g0 * HID + co];
      v1[k] = *(const short8_t*)&h1h[(size_t)g1 * HID + co];
      v2[k] = *(const short8_t*)&h1h[(size_t)g2 * HID + co];
      v3[k] = *(const short8_t*)&h1h[(size_t)g3 * HID + co];
    }
#pragma unroll
    for (int k = 0; k < 3; k++) {
      float a[8];
      float k0 = (0 < tlen[k]) ? 1.f : 0.f;
      float k1 = (1 < tlen[k]) ? 1.f : 0.f;
      float k2 = (2 < tlen[k]) ? 1.f : 0.f;
      float k3 = (3 < tlen[k]) ? 1.f : 0.f;
#pragma unroll
      for (int i = 0; i < 8; i++)
        a[i] = k0 * bf2f(v0[k][i]) + k1 * bf2f(v1[k][i]) + k2 * bf2f(v2[k][i]) +
               k3 * bf2f(v3[k][i]);
      // rare tail: scan tiny LDS overflow list
      for (int k3_ = 0; k3_ < ovn; k3_++) {
        unsigned ov = ovf_s[k3_];
        if ((int)(ov >> 19) == tslot[k]) {
          short8_t u = *(const short8_t*)&h1h[(size_t)(ov & 0x7FFFF) * HID + s_ * 32 +
                                              tq[k] * 8];
#pragma unroll
          for (int i = 0; i < 8; i++) a[i] += bf2f(u[i]);
        }
      }
      float inv = 1.f / fmaxf((float)tlen[k], 1.f);
#pragma unroll
      for (int i = 0; i < 8; i++) a[i] *= inv;
      short8_t hi, lo;
      split8(a, &hi, &lo);
      int qs = tq[k] ^ (tslot[k] & 3);
      *(short8_t*)&gh_s[tslot[k]][qs][0] = hi;
      *(short8_t*)&gl_s[tslot[k]][qs][0] = lo;
    }
    __syncthreads();

    // ---- phase Ca(s_): hi-plane MFMAs; latch a-fragments ----
    short8_t ahv[4], alv[4];
#pragma unroll
    for (int g = 0; g < 4; g++) {
      if (g == 0) {
        ahv[0] = ash[s_];
        alv[0] = asl[s_];
      } else {
        int slot = (g - 1) * 64 + w * 16 + m_;
        int qs = q ^ (slot & 3);
        ahv[g] = *(const short8_t*)&gh_s[slot][qs][0];
        alv[g] = *(const short8_t*)&gl_s[slot][qs][0];
      }
#pragma unroll
      for (int tt = 0; tt < 4; tt++) {
        int row = 16 * tt + m_;
        int cs = (g * 4 + q) ^ (row & 7);
        short8_t bh = *(const short8_t*)&lws[row][cs][0];
        acc[tt] = __builtin_amdgcn_mfma_f32_16x16x32_bf16(ahv[g], bh, acc[tt], 0, 0, 0);
        acc[tt] = __builtin_amdgcn_mfma_f32_16x16x32_bf16(alv[g], bh, acc[tt], 0, 0, 0);
      }
    }
    __syncthreads();

    // ---- phase St(s_): stage lo-plane weights for this K-half ----
#pragma unroll
    for (int i = 0; i < 4; i++) {
      int chi = t + 256 * i;
      int row = chi >> 4, c = chi & 15;
      int g = c >> 2, q2 = c & 3;
      short8_t wv = *(const short8_t*)&wtl[(size_t)row * 256 + g * 64 + s_ * 32 + q2 * 8];
      *(short8_t*)&lws[row][c ^ (row & 7)][0] = wv;
    }
    __syncthreads();

    // ---- phase Cb(s_): lo-plane MFMAs (a-fragments from regs) ----
#pragma unroll
    for (int g = 0; g < 4; g++) {
#pragma unroll
      for (int tt = 0; tt < 4; tt++) {
        int row = 16 * tt + m_;
        int cs = (g * 4 + q) ^ (row & 7);
        short8_t bl = *(const short8_t*)&lws[row][cs][0];
        acc[tt] = __builtin_amdgcn_mfma_f32_16x16x32_bf16(ahv[g], bl, acc[tt], 0, 0, 0);
      }
    }
    if (s_ == 0) __syncthreads();  // protect gh/gl + lws before S1 overwrites
  }

  // ---- pooled epilogue ----
  float bia[4], lw0[4], lw1[4];
#pragma unroll
  for (int tt = 0; tt < 4; tt++) {
    int col = 16 * tt + m_;
    bia[tt] = bias[col];
    lw0[tt] = linW[col * 2 + 0];
    lw1[tt] = linW[col * 2 + 1];
  }
#pragma unroll
  for (int reg = 0; reg < 4; reg++) {
    int node = n0b + w * 16 + q * 4 + reg;
    float p0 = 0.f, p1 = 0.f;
#pragma unroll
    for (int tt = 0; tt < 4; tt++) {
      float v = fmaxf(acc[tt][reg] + bia[tt], 0.f);
      p0 += v * lw0[tt];
      p1 += v * lw1[tt];
    }
#pragma unroll
    for (int o = 1; o < 16; o <<= 1) {
      p0 += __shfl_xor(p0, o, 64);
      p1 += __shfl_xor(p1, o, 64);
    }
    if (m_ == 0 && node < N) {
      int g = batch[node];
      atomicAdd(&gs[g * 2 + 0], p0);
      atomicAdd(&gs[g * 2 + 1], p1);
      atomicAdd(&gc[g], 1.0f);
    }
  }
}

__global__ __launch_bounds__(256) void final_k(const float* __restrict__ gs,
                                               const float* __restrict__ gc,
                                               const float* __restrict__ linb,
                                               float* __restrict__ out, int G) {
  int i = blockIdx.x * 256 + threadIdx.x;
  if (i >= G * 2) return;
  int g = i >> 1, o = i & 1;
  out[i] = gs[i] / fmaxf(gc[g], 1.0f) + linb[o];
}

extern "C" void kernel_launch(void* const* d_in, const int* in_sizes, int n_in,
                              void* d_out, int out_size, void* d_ws, size_t ws_size,
                              hipStream_t stream) {
  const int* sid = (const int*)d_in[0];
  const int* cid = (const int*)d_in[1];
  const int* pid = (const int*)d_in[2];
  const int* ei = (const int*)d_in[3];
  const int* et = (const int*)d_in[4];
  const int* batch = (const int*)d_in[5];
  const float* se = (const float*)d_in[7];
  const float* ce = (const float*)d_in[8];
  const float* pe = (const float*)d_in[9];
  const float* W1 = (const float*)d_in[10];
  const float* root1 = (const float*)d_in[11];
  const float* b1 = (const float*)d_in[12];
  const float* W2 = (const float*)d_in[13];
  const float* root2 = (const float*)d_in[14];
  const float* b2 = (const float*)d_in[15];
  const float* linW = (const float*)d_in[16];
  const float* linb = (const float*)d_in[17];
  float* out = (float*)d_out;

  const int N = in_sizes[0];
  const int E = in_sizes[4];
  const int G = out_size / 2;
  const int* src = ei;
  const int* dst = ei + E;
  const int NBk = (N + 63) / 64;     // buckets == fused-layer blocks
  const int NBa = (NBk + 15) & ~15;  // aligned allocation

  // ---- workspace layout (16B-aligned blocks) ----
  char* w = (char*)d_ws;
  short* h1h = (short*)w;  w += (size_t)N * HID * sizeof(short);
  short* h1l = (short*)w;  w += (size_t)N * HID * sizeof(short);
  short* xh = (short*)w;   w += (size_t)N * EMB * sizeof(short);
  short* xl = (short*)w;   w += (size_t)N * EMB * sizeof(short);
  float* gs = (float*)w;   w += (size_t)G * 2 * sizeof(float);
  float* gc = (float*)w;   w += (size_t)G * sizeof(float);
  int* bcur = (int*)w;     w += (size_t)NBa * 16 * sizeof(int);      // 64B-padded cursors
  unsigned* pk = (unsigned*)w; w += (size_t)NBa * BCAP * sizeof(unsigned);  // 19.2 MB
  short* w1h = (short*)w;  w += (size_t)64 * 128 * sizeof(short);
  short* w1l = (short*)w;  w += (size_t)64 * 128 * sizeof(short);
  short* w2h = (short*)w;  w += (size_t)64 * 256 * sizeof(short);
  short* w2l = (short*)w;  w += (size_t)64 * 256 * sizeof(short);
  if ((size_t)(w - (char*)d_ws) > ws_size) return;  // fail loudly, no OOB

  hipMemsetAsync(bcur, 0, (size_t)NBa * 16 * sizeof(int), stream);
  hipMemsetAsync(gs, 0, (size_t)G * 3 * sizeof(float), stream);

  int prep_n = N * 8;  // covers E (1.5M) and weight ranges too for this problem size
  if (prep_n < E) prep_n = E;
  if (prep_n < 64 * 256) prep_n = 64 * 256;
  prep_k<<<(prep_n + 255) / 256, 256, 0, stream>>>(sid, cid, pid, se, ce, pe, xh, xl, src,
                                                   dst, et, bcur, pk, root1, W1, root2, W2,
                                                   w1h, w1l, w2h, w2l, N, E);

  l1fused_k<<<NBk, 256, 0, stream>>>(xh, xl, bcur, pk, w1h, w1l, b1, h1h, h1l, N);
  l2fused_k<<<NBk, 256, 0, stream>>>(h1h, h1l, bcur, pk, w2h, w2l, b2, linW, batch, gs, gc,
                                     N);
  final_k<<<(G * 2 + 255) / 256, 256, 0, stream>>>(gs, gc, linb, out, G);
}

// Round 15
// 379.567 us; speedup vs baseline: 3.0014x; 1.0196x over previous
//
#include <hip/hip_runtime.h>
#include <hip/hip_bf16.h>

#define NREL 3
#define EMB 32
#define HID 64
#define OVCAP 1024
#define BCAP 1024  // per-bucket pk capacity; buckets Poisson(~320), P(>1024)~e^-487

typedef __attribute__((ext_vector_type(8))) short short8_t;
typedef __attribute__((ext_vector_type(4))) short short4_t;
typedef __attribute__((ext_vector_type(4))) float f32x4;

__device__ inline short f2bf(float v) {
  __hip_bfloat16 b = __float2bfloat16(v);
  short s;
  __builtin_memcpy(&s, &b, 2);
  return s;
}
__device__ inline float bf2f(short s) {
  __hip_bfloat16 b;
  __builtin_memcpy(&b, &s, 2);
  return __bfloat162float(b);
}
__device__ inline void split8(const float* v, short8_t* h, short8_t* l) {
#pragma unroll
  for (int i = 0; i < 8; i++) {
    short hh = f2bf(v[i]);
    (*h)[i] = hh;
    (*l)[i] = f2bf(v[i] - bf2f(hh));
  }
}

// ---- fused prep: embedding (hi/lo) + DIRECT bucket append + weight prep ----
__global__ __launch_bounds__(256) void prep_k(
    const int* __restrict__ sid, const int* __restrict__ cid, const int* __restrict__ pid,
    const float* __restrict__ se, const float* __restrict__ ce, const float* __restrict__ pe,
    short* __restrict__ xh, short* __restrict__ xl,
    const int* __restrict__ src, const int* __restrict__ dst, const int* __restrict__ et,
    int* __restrict__ bcur, unsigned* __restrict__ pk,
    const float* __restrict__ root1, const float* __restrict__ W1,
    const float* __restrict__ root2, const float* __restrict__ W2,
    short* __restrict__ w1h, short* __restrict__ w1l,
    short* __restrict__ w2h, short* __restrict__ w2l, int N, int E) {
  int i = blockIdx.x * 256 + threadIdx.x;
  if (i < N * 8) {  // embedding: one float4 slice per thread
    int n = i >> 3, cg = i & 7;
    const float4 a = *(const float4*)&se[sid[n] * EMB + cg * 4];
    const float4 b = *(const float4*)&ce[cid[n] * EMB + cg * 4];
    const float4 c = *(const float4*)&pe[pid[n] * EMB + cg * 4];
    float v[4];
    v[0] = a.x + b.x + c.x; v[1] = a.y + b.y + c.y;
    v[2] = a.z + b.z + c.z; v[3] = a.w + b.w + c.w;
    short4_t h, l;
#pragma unroll
    for (int j = 0; j < 4; j++) {
      short hh = f2bf(v[j]);
      h[j] = hh;
      l[j] = f2bf(v[j] - bf2f(hh));
    }
    *(short4_t*)&xh[(size_t)n * EMB + cg * 4] = h;
    *(short4_t*)&xl[(size_t)n * EMB + cg * 4] = l;
  }
  if (i < E) {  // direct bucket append: histogram atomic IS the append atomic
    int d = dst[i];
    int b = d >> 6;
    int j = atomicAdd(&bcur[b * 16], 1);  // one counter per 64B line
    if (j < BCAP)
      pk[(size_t)b * BCAP + j] =
          ((unsigned)(d & 63) << 21) | ((unsigned)et[i] << 19) | (unsigned)src[i];
  }
  if (i < 64 * 128) {  // layer-1 weights
    int k = i >> 6, n = i & 63;
    float v = (k < EMB) ? root1[k * 64 + n] : W1[(k - EMB) * 64 + n];
    short h = f2bf(v);
    w1h[n * 128 + k] = h;
    w1l[n * 128 + k] = f2bf(v - bf2f(h));
  }
  if (i < 64 * 256) {  // layer-2 weights
    int k = i >> 6, n = i & 63;
    float v = (k < HID) ? root2[k * 64 + n] : W2[(k - HID) * 64 + n];
    short h = f2bf(v);
    w2h[n * 256 + k] = h;
    w2l[n * 256 + k] = f2bf(v - bf2f(h));
  }
}

// ====== layer-1: in-LDS CSR build + consumer-aligned register gather + phased MFMA ======
__global__ __launch_bounds__(256) void l1fused_k(
    const short* __restrict__ xh, const short* __restrict__ xl,
    const int* __restrict__ bcur, const unsigned* __restrict__ pk,
    const short* __restrict__ wth, const short* __restrict__ wtl,
    const float* __restrict__ bias, short* __restrict__ h1h, short* __restrict__ h1l, int N) {
  __shared__ __align__(16) short lws[64][16][8];  // 16 KB (one plane)
  __shared__ __align__(16) int4 mid_s[192];       //  3 KB (first-4 ids)
  __shared__ int cnt_s[192];
  __shared__ unsigned ovf_s[OVCAP];               //  4 KB (slot<<19 | src)
  __shared__ int ovfn_s;

  const int t = threadIdx.x;
  const int lane = t & 63, w = t >> 6;
  const int m_ = lane & 15, q = lane >> 4;
  const int n0b = blockIdx.x * 64;

  // ---- phase A: hi-plane weights -> LDS, self -> regs, init build state ----
  int node_c = n0b + w * 16 + m_;
  if (node_c >= N) node_c = N - 1;
  short8_t ah0 = *(const short8_t*)&xh[(size_t)node_c * EMB + q * 8];
  short8_t al0 = *(const short8_t*)&xl[(size_t)node_c * EMB + q * 8];
#pragma unroll
  for (int i = 0; i < 4; i++) {
    int chi = t + 256 * i;
    int row = chi >> 4, c = chi & 15;
    short8_t wv = *(const short8_t*)&wth[(size_t)row * 128 + c * 8];
    *(short8_t*)&lws[row][c ^ (row & 7)][0] = wv;
  }
  if (t < 192) cnt_s[t] = 0;
  if (t == 0) ovfn_s = 0;
  __syncthreads();

  // ---- phase B: in-LDS CSR build (1 LDS atomic/edge) ----
  {
    int ne = bcur[blockIdx.x * 16];
    if (ne > BCAP) ne = BCAP;
    const size_t base = (size_t)blockIdx.x * BCAP;
    for (int e = t; e < ne; e += 256) {
      unsigned p = pk[base + e];
      int srcn = (int)(p & 0x7FFFF);
      int slot = (int)((p >> 19) & 3) * 64 + (int)(p >> 21);
      int j = atomicAdd(&cnt_s[slot], 1);
      if (j < 4) ((int*)&mid_s[slot])[j] = srcn;
      else {
        int k2 = atomicAdd(&ovfn_s, 1);
        if (k2 < OVCAP) ovf_s[k2] = ((unsigned)slot << 19) | (unsigned)srcn;
      }
    }
  }
  __syncthreads();

  // ---- phase S': consumer-aligned gather -> REGISTER fragments (no LDS round-trip) ----
  short8_t ahv[4], alv[4];
  ahv[0] = ah0;
  alv[0] = al0;
  {
    int ovn = ovfn_s;
    if (ovn > OVCAP) ovn = OVCAP;
    int tslot[3], tlen[3];
    int4 tid4[3];
#pragma unroll
    for (int k = 0; k < 3; k++) {
      tslot[k] = k * 64 + w * 16 + m_;  // the slots THIS thread consumes (g=k+1)
      tid4[k] = mid_s[tslot[k]];
      tlen[k] = cnt_s[tslot[k]];
    }
    short8_t v0[3], v1[3], v2[3], v3[3];
#pragma unroll
    for (int k = 0; k < 3; k++) {
      int nself = n0b + (tslot[k] & 63);
      if (nself >= N) nself = N - 1;
      int g0 = (0 < tlen[k]) ? tid4[k].x : nself;
      int g1 = (1 < tlen[k]) ? tid4[k].y : nself;
      int g2 = (2 < tlen[k]) ? tid4[k].z : nself;
      int g3 = (3 < tlen[k]) ? tid4[k].w : nself;
      size_t co = (size_t)q * 8;
      v0[k] = *(const short8_t*)&xh[(size_t)g0 * EMB + co];
      v1[k] = *(const short8_t*)&xh[(size_t)g1 * EMB + co];
      v2[k] = *(const short8_t*)&xh[(size_t)g2 * EMB + co];
      v3[k] = *(const short8_t*)&xh[(size_t)g3 * EMB + co];
    }
#pragma unroll
    for (int k = 0; k < 3; k++) {
      float a[8];
      float k0 = (0 < tlen[k]) ? 1.f : 0.f;
      float k1 = (1 < tlen[k]) ? 1.f : 0.f;
      float k2 = (2 < tlen[k]) ? 1.f : 0.f;
      float k3 = (3 < tlen[k]) ? 1.f : 0.f;
#pragma unroll
      for (int i = 0; i < 8; i++)
        a[i] = k0 * bf2f(v0[k][i]) + k1 * bf2f(v1[k][i]) + k2 * bf2f(v2[k][i]) +
               k3 * bf2f(v3[k][i]);
      // rare tail: scan tiny LDS overflow list (~6 entries/bucket)
      for (int k3_ = 0; k3_ < ovn; k3_++) {
        unsigned ov = ovf_s[k3_];
        if ((int)(ov >> 19) == tslot[k]) {
          short8_t u = *(const short8_t*)&xh[(size_t)(ov & 0x7FFFF) * EMB + q * 8];
#pragma unroll
          for (int i = 0; i < 8; i++) a[i] += bf2f(u[i]);
        }
      }
      float inv = 1.f / fmaxf((float)tlen[k], 1.f);
#pragma unroll
      for (int i = 0; i < 8; i++) a[i] *= inv;
      split8(a, &ahv[k + 1], &alv[k + 1]);
    }
  }

  // ---- phase Ca: hi-plane MFMAs (lws stable since phase A; no barrier needed) ----
  f32x4 acc[4];
#pragma unroll
  for (int i = 0; i < 4; i++) acc[i] = (f32x4){0.f, 0.f, 0.f, 0.f};
#pragma unroll
  for (int g = 0; g < 4; g++) {
#pragma unroll
    for (int tt = 0; tt < 4; tt++) {
      int row = 16 * tt + m_;
      int cs = (g * 4 + q) ^ (row & 7);
      short8_t bh = *(const short8_t*)&lws[row][cs][0];
      acc[tt] = __builtin_amdgcn_mfma_f32_16x16x32_bf16(ahv[g], bh, acc[tt], 0, 0, 0);
      acc[tt] = __builtin_amdgcn_mfma_f32_16x16x32_bf16(alv[g], bh, acc[tt], 0, 0, 0);
    }
  }
  __syncthreads();

  // ---- phase St: stage lo-plane weights ----
#pragma unroll
  for (int i = 0; i < 4; i++) {
    int chi = t + 256 * i;
    int row = chi >> 4, c = chi & 15;
    short8_t wv = *(const short8_t*)&wtl[(size_t)row * 128 + c * 8];
    *(short8_t*)&lws[row][c ^ (row & 7)][0] = wv;
  }
  __syncthreads();

  // ---- phase Cb: lo-plane MFMAs ----
#pragma unroll
  for (int g = 0; g < 4; g++) {
#pragma unroll
    for (int tt = 0; tt < 4; tt++) {
      int row = 16 * tt + m_;
      int cs = (g * 4 + q) ^ (row & 7);
      short8_t bl = *(const short8_t*)&lws[row][cs][0];
      acc[tt] = __builtin_amdgcn_mfma_f32_16x16x32_bf16(ahv[g], bl, acc[tt], 0, 0, 0);
    }
  }
  // epilogue: bias + relu + hi/lo split store
#pragma unroll
  for (int tt = 0; tt < 4; tt++) {
    float bia = bias[16 * tt + m_];
#pragma unroll
    for (int reg = 0; reg < 4; reg++) {
      int node = n0b + w * 16 + q * 4 + reg;
      if (node < N) {
        float val = fmaxf(acc[tt][reg] + bia, 0.f);
        short hh = f2bf(val);
        h1h[(size_t)node * HID + 16 * tt + m_] = hh;
        h1l[(size_t)node * HID + 16 * tt + m_] = f2bf(val - bf2f(hh));
      }
    }
  }
}

// ====== layer-2: in-LDS CSR build + MERGED both-K-half register gather + phased MFMA ======
// Both K-half batches issued back-to-back: batch-1 re-reads the same 128B rows while
// L1-resident -> each h1 row fetched from L2/HBM once (FETCH ~halved vs separated passes).
__global__ __launch_bounds__(256) void l2fused_k(
    const short* __restrict__ h1h, const short* __restrict__ h1l,
    const int* __restrict__ bcur, const unsigned* __restrict__ pk,
    const short* __restrict__ wth, const short* __restrict__ wtl,
    const float* __restrict__ bias, const float* __restrict__ linW,
    const int* __restrict__ batch, float* __restrict__ gs, float* __restrict__ gc, int N) {
  __shared__ __align__(16) short lws[64][16][8];  // 16 KB (one plane, one K-half)
  __shared__ __align__(16) int4 mid_s[192];       //  3 KB
  __shared__ int cnt_s[192];
  __shared__ unsigned ovf_s[OVCAP];               //  4 KB
  __shared__ int ovfn_s;

  const int t = threadIdx.x;
  const int lane = t & 63, w = t >> 6;
  const int m_ = lane & 15, q = lane >> 4;
  const int n0b = blockIdx.x * 64;

  // ---- phase A: hi-weights(s0) -> LDS; init build state ----
  int node_c = n0b + w * 16 + m_;
  if (node_c >= N) node_c = N - 1;
#pragma unroll
  for (int i = 0; i < 4; i++) {
    int chi = t + 256 * i;
    int row = chi >> 4, c = chi & 15;
    int g = c >> 2, qq = c & 3;
    short8_t wv = *(const short8_t*)&wth[(size_t)row * 256 + g * 64 + 0 * 32 + qq * 8];
    *(short8_t*)&lws[row][c ^ (row & 7)][0] = wv;
  }
  if (t < 192) cnt_s[t] = 0;
  if (t == 0) ovfn_s = 0;
  __syncthreads();

  // ---- phase B: in-LDS CSR build (1 LDS atomic/edge) ----
  {
    int ne = bcur[blockIdx.x * 16];
    if (ne > BCAP) ne = BCAP;
    const size_t base = (size_t)blockIdx.x * BCAP;
    for (int e = t; e < ne; e += 256) {
      unsigned p = pk[base + e];
      int srcn = (int)(p & 0x7FFFF);
      int slot = (int)((p >> 19) & 3) * 64 + (int)(p >> 21);
      int j = atomicAdd(&cnt_s[slot], 1);
      if (j < 4) ((int*)&mid_s[slot])[j] = srcn;
      else {
        int k2 = atomicAdd(&ovfn_s, 1);
        if (k2 < OVCAP) ovf_s[k2] = ((unsigned)slot << 19) | (unsigned)srcn;
      }
    }
  }
  __syncthreads();

  // ---- phase S'': merged both-K-half consumer-aligned gather -> register fragments ----
  short8_t ahv0[4], alv0[4], ahv1[4], alv1[4];
  {
    // self fragments (both halves)
    ahv0[0] = *(const short8_t*)&h1h[(size_t)node_c * HID + q * 8];
    alv0[0] = *(const short8_t*)&h1l[(size_t)node_c * HID + q * 8];
    ahv1[0] = *(const short8_t*)&h1h[(size_t)node_c * HID + 32 + q * 8];
    alv1[0] = *(const short8_t*)&h1l[(size_t)node_c * HID + 32 + q * 8];
    int ovn = ovfn_s;
    if (ovn > OVCAP) ovn = OVCAP;
    int tslot[3], tlen[3];
    int4 tid4[3];
    int gid[3][4];
#pragma unroll
    for (int k = 0; k < 3; k++) {
      tslot[k] = k * 64 + w * 16 + m_;
      tid4[k] = mid_s[tslot[k]];
      tlen[k] = cnt_s[tslot[k]];
      int nself = n0b + (tslot[k] & 63);
      if (nself >= N) nself = N - 1;
      gid[k][0] = (0 < tlen[k]) ? tid4[k].x : nself;
      gid[k][1] = (1 < tlen[k]) ? tid4[k].y : nself;
      gid[k][2] = (2 < tlen[k]) ? tid4[k].z : nself;
      gid[k][3] = (3 < tlen[k]) ? tid4[k].w : nself;
    }
    float a0[3][8], a1[3][8];
    // batch half-0: 12 independent line-opening loads
    {
      short8_t v0[3], v1[3], v2[3], v3[3];
#pragma unroll
      for (int k = 0; k < 3; k++) {
        size_t co = (size_t)q * 8;
        v0[k] = *(const short8_t*)&h1h[(size_t)gid[k][0] * HID + co];
        v1[k] = *(const short8_t*)&h1h[(size_t)gid[k][1] * HID + co];
        v2[k] = *(const short8_t*)&h1h[(size_t)gid[k][2] * HID + co];
        v3[k] = *(const short8_t*)&h1h[(size_t)gid[k][3] * HID + co];
      }
#pragma unroll
      for (int k = 0; k < 3; k++) {
        float k0 = (0 < tlen[k]) ? 1.f : 0.f;
        float k1 = (1 < tlen[k]) ? 1.f : 0.f;
        float k2 = (2 < tlen[k]) ? 1.f : 0.f;
        float k3 = (3 < tlen[k]) ? 1.f : 0.f;
#pragma unroll
        for (int i = 0; i < 8; i++)
          a0[k][i] = k0 * bf2f(v0[k][i]) + k1 * bf2f(v1[k][i]) + k2 * bf2f(v2[k][i]) +
                     k3 * bf2f(v3[k][i]);
      }
    }
    // batch half-1: same rows +64B -> L1-resident lines, no new L2/HBM fetch
    {
      short8_t v0[3], v1[3], v2[3], v3[3];
#pragma unroll
      for (int k = 0; k < 3; k++) {
        size_t co = 32 + (size_t)q * 8;
        v0[k] = *(const short8_t*)&h1h[(size_t)gid[k][0] * HID + co];
        v1[k] = *(const short8_t*)&h1h[(size_t)gid[k][1] * HID + co];
        v2[k] = *(const short8_t*)&h1h[(size_t)gid[k][2] * HID + co];
        v3[k] = *(const short8_t*)&h1h[(size_t)gid[k][3] * HID + co];
      }
#pragma unroll
      for (int k = 0; k < 3; k++) {
        float k0 = (0 < tlen[k]) ? 1.f : 0.f;
        float k1 = (1 < tlen[k]) ? 1.f : 0.f;
        float k2 = (2 < tlen[k]) ? 1.f : 0.f;
        float k3 = (3 < tlen[k]) ? 1.f : 0.f;
#pragma unroll
        for (int i = 0; i < 8; i++)
          a1[k][i] = k0 * bf2f(v0[k][i]) + k1 * bf2f(v1[k][i]) + k2 * bf2f(v2[k][i]) +
                     k3 * bf2f(v3[k][i]);
      }
    }
    // rare tail: overflow entries contribute to both halves
#pragma unroll
    for (int k = 0; k < 3; k++) {
      for (int k3_ = 0; k3_ < ovn; k3_++) {
        unsigned ov = ovf_s[k3_];
        if ((int)(ov >> 19) == tslot[k]) {
          const short* p = &h1h[(size_t)(ov & 0x7FFFF) * HID];
          short8_t u0 = *(const short8_t*)&p[q * 8];
          short8_t u1 = *(const short8_t*)&p[32 + q * 8];
#pragma unroll
          for (int i = 0; i < 8; i++) {
            a0[k][i] += bf2f(u0[i]);
            a1[k][i] += bf2f(u1[i]);
          }
        }
      }
      float inv = 1.f / fmaxf((float)tlen[k], 1.f);
#pragma unroll
      for (int i = 0; i < 8; i++) {
        a0[k][i] *= inv;
        a1[k][i] *= inv;
      }
      split8(a0[k], &ahv0[k + 1], &alv0[k + 1]);
      split8(a1[k], &ahv1[k + 1], &alv1[k + 1]);
    }
  }

  // ---- weight-phase sequence: 4 stages x MFMA, fragments from registers ----
  f32x4 acc[4];
#pragma unroll
  for (int i = 0; i < 4; i++) acc[i] = (f32x4){0.f, 0.f, 0.f, 0.f};
#pragma unroll
  for (int s_ = 0; s_ < 2; s_++) {
    if (s_ == 1) {  // re-stage hi-weights for K-half 1 (lws fully consumed; barrier passed)
#pragma unroll
      for (int i = 0; i < 4; i++) {
        int chi = t + 256 * i;
        int row = chi >> 4, c = chi & 15;
        int g = c >> 2, q2 = c & 3;
        short8_t wv = *(const short8_t*)&wth[(size_t)row * 256 + g * 64 + 32 + q2 * 8];
        *(short8_t*)&lws[row][c ^ (row & 7)][0] = wv;
      }
      __syncthreads();
    }
    // Ca(s_): hi-plane MFMAs
#pragma unroll
    for (int g = 0; g < 4; g++) {
      short8_t ah = (s_ == 0) ? ahv0[g] : ahv1[g];
      short8_t al = (s_ == 0) ? alv0[g] : alv1[g];
#pragma unroll
      for (int tt = 0; tt < 4; tt++) {
        int row = 16 * tt + m_;
        int cs = (g * 4 + q) ^ (row & 7);
        short8_t bh = *(const short8_t*)&lws[row][cs][0];
        acc[tt] = __builtin_amdgcn_mfma_f32_16x16x32_bf16(ah, bh, acc[tt], 0, 0, 0);
        acc[tt] = __builtin_amdgcn_mfma_f32_16x16x32_bf16(al, bh, acc[tt], 0, 0, 0);
      }
    }
    __syncthreads();
    // St(s_): stage lo-plane weights for this K-half
#pragma unroll
    for (int i = 0; i < 4; i++) {
      int chi = t + 256 * i;
      int row = chi >> 4, c = chi & 15;
      int g = c >> 2, q2 = c & 3;
      short8_t wv = *(const short8_t*)&wtl[(size_t)row * 256 + g * 64 + s_ * 32 + q2 * 8];
      *(short8_t*)&lws[row][c ^ (row & 7)][0] = wv;
    }
    __syncthreads();
    // Cb(s_): lo-plane MFMAs
#pragma unroll
    for (int g = 0; g < 4; g++) {
      short8_t ah = (s_ == 0) ? ahv0[g] : ahv1[g];
#pragma unroll
      for (int tt = 0; tt < 4; tt++) {
        int row = 16 * tt + m_;
        int cs = (g * 4 + q) ^ (row & 7);
        short8_t bl = *(const short8_t*)&lws[row][cs][0];
        acc[tt] = __builtin_amdgcn_mfma_f32_16x16x32_bf16(ah, bl, acc[tt], 0, 0, 0);
      }
    }
    if (s_ == 0) __syncthreads();  // protect lws before next hi-stage
  }

  // ---- pooled epilogue ----
  float bia[4], lw0[4], lw1[4];
#pragma unroll
  for (int tt = 0; tt < 4; tt++) {
    int col = 16 * tt + m_;
    bia[tt] = bias[col];
    lw0[tt] = linW[col * 2 + 0];
    lw1[tt] = linW[col * 2 + 1];
  }
#pragma unroll
  for (int reg = 0; reg < 4; reg++) {
    int node = n0b + w * 16 + q * 4 + reg;
    float p0 = 0.f, p1 = 0.f;
#pragma unroll
    for (int tt = 0; tt < 4; tt++) {
      float v = fmaxf(acc[tt][reg] + bia[tt], 0.f);
      p0 += v * lw0[tt];
      p1 += v * lw1[tt];
    }
#pragma unroll
    for (int o = 1; o < 16; o <<= 1) {
      p0 += __shfl_xor(p0, o, 64);
      p1 += __shfl_xor(p1, o, 64);
    }
    if (m_ == 0 && node < N) {
      int g = batch[node];
      atomicAdd(&gs[g * 2 + 0], p0);
      atomicAdd(&gs[g * 2 + 1], p1);
      atomicAdd(&gc[g], 1.0f);
    }
  }
}

__global__ __launch_bounds__(256) void final_k(const float* __restrict__ gs,
                                               const float* __restrict__ gc,
                                               const float* __restrict__ linb,
                                               float* __restrict__ out, int G) {
  int i = blockIdx.x * 256 + threadIdx.x;
  if (i >= G * 2) return;
  int g = i >> 1, o = i & 1;
  out[i] = gs[i] / fmaxf(gc[g], 1.0f) + linb[o];
}

extern "C" void kernel_launch(void* const* d_in, const int* in_sizes, int n_in,
                              void* d_out, int out_size, void* d_ws, size_t ws_size,
                              hipStream_t stream) {
  const int* sid = (const int*)d_in[0];
  const int* cid = (const int*)d_in[1];
  const int* pid = (const int*)d_in[2];
  const int* ei = (const int*)d_in[3];
  const int* et = (const int*)d_in[4];
  const int* batch = (const int*)d_in[5];
  const float* se = (const float*)d_in[7];
  const float* ce = (const float*)d_in[8];
  const float* pe = (const float*)d_in[9];
  const float* W1 = (const float*)d_in[10];
  const float* root1 = (const float*)d_in[11];
  const float* b1 = (const float*)d_in[12];
  const float* W2 = (const float*)d_in[13];
  const float* root2 = (const float*)d_in[14];
  const float* b2 = (const float*)d_in[15];
  const float* linW = (const float*)d_in[16];
  const float* linb = (const float*)d_in[17];
  float* out = (float*)d_out;

  const int N = in_sizes[0];
  const int E = in_sizes[4];
  const int G = out_size / 2;
  const int* src = ei;
  const int* dst = ei + E;
  const int NBk = (N + 63) / 64;     // buckets == fused-layer blocks
  const int NBa = (NBk + 15) & ~15;  // aligned allocation

  // ---- workspace layout (16B-aligned blocks) ----
  char* w = (char*)d_ws;
  short* h1h = (short*)w;  w += (size_t)N * HID * sizeof(short);
  short* h1l = (short*)w;  w += (size_t)N * HID * sizeof(short);
  short* xh = (short*)w;   w += (size_t)N * EMB * sizeof(short);
  short* xl = (short*)w;   w += (size_t)N * EMB * sizeof(short);
  float* gs = (float*)w;   w += (size_t)G * 2 * sizeof(float);
  float* gc = (float*)w;   w += (size_t)G * sizeof(float);
  int* bcur = (int*)w;     w += (size_t)NBa * 16 * sizeof(int);      // 64B-padded cursors
  unsigned* pk = (unsigned*)w; w += (size_t)NBa * BCAP * sizeof(unsigned);  // 19.2 MB
  short* w1h = (short*)w;  w += (size_t)64 * 128 * sizeof(short);
  short* w1l = (short*)w;  w += (size_t)64 * 128 * sizeof(short);
  short* w2h = (short*)w;  w += (size_t)64 * 256 * sizeof(short);
  short* w2l = (short*)w;  w += (size_t)64 * 256 * sizeof(short);
  if ((size_t)(w - (char*)d_ws) > ws_size) return;  // fail loudly, no OOB

  hipMemsetAsync(bcur, 0, (size_t)NBa * 16 * sizeof(int), stream);
  hipMemsetAsync(gs, 0, (size_t)G * 3 * sizeof(float), stream);

  int prep_n = N * 8;  // covers E (1.5M) and weight ranges too for this problem size
  if (prep_n < E) prep_n = E;
  if (prep_n < 64 * 256) prep_n = 64 * 256;
  prep_k<<<(prep_n + 255) / 256, 256, 0, stream>>>(sid, cid, pid, se, ce, pe, xh, xl, src,
                                                   dst, et, bcur, pk, root1, W1, root2, W2,
                                                   w1h, w1l, w2h, w2l, N, E);

  l1fused_k<<<NBk, 256, 0, stream>>>(xh, xl, bcur, pk, w1h, w1l, b1, h1h, h1l, N);
  l2fused_k<<<NBk, 256, 0, stream>>>(h1h, h1l, bcur, pk, w2h, w2l, b2, linW, batch, gs, gc,
                                     N);
  final_k<<<(G * 2 + 255) / 256, 256, 0, stream>>>(gs, gc, linb, out, G);
}